// Round 11
// baseline (1686.833 us; speedup 1.0000x reference)
//
#include <hip/hip_runtime.h>
#include <math.h>

// Problem constants: T=2048, B=256, H=128, IN_DIM=1, NUM_DATA=4096
#define T_STEPS 2048
#define BATCH   256
#define HDIM    128

// R11: forbid AGPR allocation. R2-R10 evidence: the allocator grants only
// ~36% of the unified-file budget as arch VGPRs and parks the rest (the
// weights) in AGPRs; v_fma_f32 cannot source AGPRs (R9 compile error), so
// every parked weight pays >=1 v_accvgpr move per use (~850 excess cyc/step
// at R10). amdgpu_agpr_alloc(0) (LLVM "amdgpu-agpr-alloc") disables AGPRs
// -> all ~160 live floats must be arch VGPRs (fits 256/wave at 2 waves/EU).
// __has_attribute-guarded: unsupported toolchain degrades to exactly R10.
#if defined(__has_attribute)
#  if __has_attribute(amdgpu_agpr_alloc)
#    define NO_AGPR __attribute__((amdgpu_agpr_alloc(0)))
#  elif __has_attribute(amdgpu_num_agpr)
#    define NO_AGPR __attribute__((amdgpu_num_agpr(0)))
#  else
#    define NO_AGPR
#  endif
#else
#  define NO_AGPR
#endif

__device__ __forceinline__ float fast_rcp(float x) { return __builtin_amdgcn_rcpf(x); }
__device__ __forceinline__ float sigmoid_f(float x) { return fast_rcp(1.0f + __expf(-x)); }
__device__ __forceinline__ float tanh_f(float x) {
    float e = __expf(2.0f * x);
    return 1.0f - 2.0f * fast_rcp(e + 1.0f);
}

#define REP8(M) M(0) M(1) M(2) M(3) M(4) M(5) M(6) M(7)

// Structure = R7/R10 (verified absmax 0.0, SQ_LDS_BANK_CONFLICT == 0,
// best dur 1680 us): 512 threads (2 waves/EU), thread -> (element
// m = tid>>2, K-quarter q = tid&3), all 4 gate rows per thread over a
// 32-wide K slice; shfl_xor(1,2) combines quarters; local activation +
// c/h update (replicated x4); h double-buffered in LDS with 36-word
// quarter bases; ONE barrier/step; wave-0 y-dot overlapped, out[] written
// one step deferred. In-loop volatile pins keep the weight values defined
// each iteration (R10: 1980->1680 us).
// Feedback fold: gates = h.(W_hh + W_ih (x) W_lin)^T + (b + W_ih*b_lin);
// t=0 corrected by -wih*y_init on iteration 0.
__global__ __launch_bounds__(512, 2) NO_AGPR
void lstm_seq_kernel(const int*   __restrict__ label,
                     const float* __restrict__ h0,     // (1, 4096, 128)
                     const float* __restrict__ W_ih,   // (512, 1)
                     const float* __restrict__ W_hh,   // (512, 128)
                     const float* __restrict__ b_ih,   // (512,)
                     const float* __restrict__ b_hh,   // (512,)
                     const float* __restrict__ W_lin,  // (1, 128)
                     const float* __restrict__ b_lin,  // (1,)
                     float*       __restrict__ out)    // (T, B, 1)
{
    const int tid   = threadIdx.x;
    const int batch = blockIdx.x;
    const int m     = tid >> 2;     // h element 0..127
    const int q     = tid & 3;      // K-quarter 0..3
    const int q8    = q * 8;        // float4 index of K-slice start

    const int ri = m, rf = m + 128, rg = m + 256, ro = m + 384;

    __shared__ float hbuf[2][160];  // quarters at 36q words (conflict-free)

    const float4* W4 = (const float4*)W_hh;   // row j = W4[j*32 ..]
    const float4* L4 = (const float4*)W_lin;  // 32 float4

    // ---- load the 4 gate-row K-slices (8 float4 each = 128 floats) ----
    #define DECL_W(i) \
        float4 wi##i = W4[ri * 32 + q8 + (i)]; \
        float4 wf##i = W4[rf * 32 + q8 + (i)]; \
        float4 wg##i = W4[rg * 32 + q8 + (i)]; \
        float4 wo##i = W4[ro * 32 + q8 + (i)];
    REP8(DECL_W)

    const float wih_i = W_ih[ri], wih_f = W_ih[rf];
    const float wih_g = W_ih[rg], wih_o = W_ih[ro];
    const float blin  = b_lin[0];

    const float bi_ = b_ih[ri] + b_hh[ri] + wih_i * blin;
    const float bf_ = b_ih[rf] + b_hh[rf] + wih_f * blin;
    const float bg_ = b_ih[rg] + b_hh[rg] + wih_g * blin;
    const float bo_ = b_ih[ro] + b_hh[ro] + wih_o * blin;

    // ---- fold feedback: W' = W_hh + wih (x) W_lin ----
    #define FOLD_W(i) { float4 lv = L4[q8 + (i)]; \
        wi##i.x = fmaf(wih_i, lv.x, wi##i.x); wi##i.y = fmaf(wih_i, lv.y, wi##i.y); \
        wi##i.z = fmaf(wih_i, lv.z, wi##i.z); wi##i.w = fmaf(wih_i, lv.w, wi##i.w); \
        wf##i.x = fmaf(wih_f, lv.x, wf##i.x); wf##i.y = fmaf(wih_f, lv.y, wf##i.y); \
        wf##i.z = fmaf(wih_f, lv.z, wf##i.z); wf##i.w = fmaf(wih_f, lv.w, wf##i.w); \
        wg##i.x = fmaf(wih_g, lv.x, wg##i.x); wg##i.y = fmaf(wih_g, lv.y, wg##i.y); \
        wg##i.z = fmaf(wih_g, lv.z, wg##i.z); wg##i.w = fmaf(wih_g, lv.w, wg##i.w); \
        wo##i.x = fmaf(wih_o, lv.x, wo##i.x); wo##i.y = fmaf(wih_o, lv.y, wo##i.y); \
        wo##i.z = fmaf(wih_o, lv.z, wo##i.z); wo##i.w = fmaf(wih_o, lv.w, wo##i.w); }
    REP8(FOLD_W)

    // in-loop pin: redefines all 16 components of group i (volatile, empty)
    #define PIN_W(i) asm volatile("" : \
        "+v"(wi##i.x), "+v"(wi##i.y), "+v"(wi##i.z), "+v"(wi##i.w), \
        "+v"(wf##i.x), "+v"(wf##i.y), "+v"(wf##i.z), "+v"(wf##i.w), \
        "+v"(wg##i.x), "+v"(wg##i.y), "+v"(wg##i.z), "+v"(wg##i.w), \
        "+v"(wo##i.x), "+v"(wo##i.y), "+v"(wo##i.z), "+v"(wo##i.w));

    // y-dot lane constants (wave 0 uses them per step)
    const int   lane = tid & 63;
    const int   ya0  = lane + ((lane >> 5) << 2);   // word of h[lane]
    const int   ya1  = ya0 + 72;                    // word of h[lane+64]
    const float wl_a = W_lin[lane];
    const float wl_b = W_lin[lane + 64];

    // ---- init h ----
    if (tid < HDIM) hbuf[0][tid + ((tid >> 5) << 2)] = h0[label[batch] * HDIM + tid];
    __syncthreads();

    // y_init (uniform across waves)
    float p0 = hbuf[0][ya0] * wl_a + hbuf[0][ya1] * wl_b;
    #pragma unroll
    for (int off = 1; off < 64; off <<= 1) p0 += __shfl_xor(p0, off, 64);
    const float y0 = p0 + blin;

    // iteration-0 biases carry the x_0 = 0 correction
    float cbi = bi_ - wih_i * y0;
    float cbf = bf_ - wih_f * y0;
    float cbg = bg_ - wih_g * y0;
    float cbo = bo_ - wih_o * y0;

    float c   = 0.0f;
    int   cur = 0;

    for (int t = 0; t < T_STEPS; ++t) {
        float* hb = hbuf[cur];

        // pins: weights opaquely redefined every iteration -> loop-carried
        REP8(PIN_W)

        // ---- deferred y of the CURRENT h (wave 0; overlaps FMA stream) ----
        if (tid < 64) {
            float yv = hb[ya0] * wl_a + hb[ya1] * wl_b;
            #pragma unroll
            for (int off = 1; off < 64; off <<= 1) yv += __shfl_xor(yv, off, 64);
            if (tid == 0 && t > 0) out[(t - 1) * BATCH + batch] = yv + blin;
        }

        // ---- 4 gate dots over this thread's K-quarter (32 FMAs each) ----
        const float4* hq = (const float4*)(hb + 36 * q);
        float ai = 0.f, af = 0.f, ag = 0.f, ao = 0.f;
        #define DOT4(i) { float4 hv = hq[(i)]; \
            ai = fmaf(hv.x, wi##i.x, ai); ai = fmaf(hv.y, wi##i.y, ai); \
            ai = fmaf(hv.z, wi##i.z, ai); ai = fmaf(hv.w, wi##i.w, ai); \
            af = fmaf(hv.x, wf##i.x, af); af = fmaf(hv.y, wf##i.y, af); \
            af = fmaf(hv.z, wf##i.z, af); af = fmaf(hv.w, wf##i.w, af); \
            ag = fmaf(hv.x, wg##i.x, ag); ag = fmaf(hv.y, wg##i.y, ag); \
            ag = fmaf(hv.z, wg##i.z, ag); ag = fmaf(hv.w, wg##i.w, ag); \
            ao = fmaf(hv.x, wo##i.x, ao); ao = fmaf(hv.y, wo##i.y, ao); \
            ao = fmaf(hv.z, wo##i.z, ao); ao = fmaf(hv.w, wo##i.w, ao); }
        REP8(DOT4)

        // ---- combine the 4 K-quarters ----
        ai += __shfl_xor(ai, 1, 64); af += __shfl_xor(af, 1, 64);
        ag += __shfl_xor(ag, 1, 64); ao += __shfl_xor(ao, 1, 64);
        ai += __shfl_xor(ai, 2, 64); af += __shfl_xor(af, 2, 64);
        ag += __shfl_xor(ag, 2, 64); ao += __shfl_xor(ao, 2, 64);

        // ---- local activation + c/h update (replicated x4 lanes) ----
        const float iv = sigmoid_f(ai + cbi);
        const float fv = sigmoid_f(af + cbf);
        const float gv = tanh_f  (ag + cbg);
        const float ov = sigmoid_f(ao + cbo);
        c = fmaf(fv, c, iv * gv);
        const float hn = ov * tanh_f(c);
        if (q == 0) hbuf[cur ^ 1][m + ((m >> 5) << 2)] = hn;

        __syncthreads();          // the ONE barrier per step
        cur ^= 1;
        cbi = bi_; cbf = bf_; cbg = bg_; cbo = bo_;   // drop t=0 correction
    }

    // final y from h_T
    if (tid < 64) {
        float yv = hbuf[cur][ya0] * wl_a + hbuf[cur][ya1] * wl_b;
        #pragma unroll
        for (int off = 1; off < 64; off <<= 1) yv += __shfl_xor(yv, off, 64);
        if (tid == 0) out[(T_STEPS - 1) * BATCH + batch] = yv + blin;
    }
}

extern "C" void kernel_launch(void* const* d_in, const int* in_sizes, int n_in,
                              void* d_out, int out_size, void* d_ws, size_t ws_size,
                              hipStream_t stream) {
    // inputs: 0 input (unused), 1 label, 2 h0, 3 W_ih, 4 W_hh,
    //         5 b_ih, 6 b_hh, 7 W_lin, 8 b_lin
    const int*   label = (const int*)  d_in[1];
    const float* h0    = (const float*)d_in[2];
    const float* W_ih  = (const float*)d_in[3];
    const float* W_hh  = (const float*)d_in[4];
    const float* b_ih  = (const float*)d_in[5];
    const float* b_hh  = (const float*)d_in[6];
    const float* W_lin = (const float*)d_in[7];
    const float* b_lin = (const float*)d_in[8];
    float* out = (float*)d_out;

    lstm_seq_kernel<<<dim3(BATCH), dim3(512), 0, stream>>>(
        label, h0, W_ih, W_hh, b_ih, b_hh, W_lin, b_lin, out);
}

// Round 13
// 1528.697 us; speedup vs baseline: 1.1034x; 1.1034x over previous
//
#include <hip/hip_runtime.h>
#include <math.h>

// Problem constants: T=2048, B=256, H=128, IN_DIM=1, NUM_DATA=4096
#define T_STEPS 2048
#define BATCH   256
#define HDIM    128

__device__ __forceinline__ float fast_rcp(float x) { return __builtin_amdgcn_rcpf(x); }
__device__ __forceinline__ float sigmoid_f(float x) { return fast_rcp(1.0f + __expf(-x)); }
__device__ __forceinline__ float tanh_f(float x) {
    float e = __expf(2.0f * x);
    return 1.0f - 2.0f * fast_rcp(e + 1.0f);
}

#define REP8(M) M(0) M(1) M(2) M(3) M(4) M(5) M(6) M(7)

// R13 = R12 (whole t-loop in one asm block, hard physical VGPRs: h v[0:31],
// wi v[32:63], wf v[64:95], wg v[96:127], wo v[128:159], acc v[160:163],
// tmp v[164:171], addr v[172:176], const v[177:186]) + THE FIX:
// R12 violated the CDNA trans-op hazard (v_exp/v_rcp result consumed by the
// NEXT VALU instruction needs >=1 wait state; compiler-generated code gets
// s_nop automatically, hand asm did not) -> stale reads -> absmax 1.2e6.
// R13 interleaves the 4 gates' activations (mul x4, exp x4, add x4, rcp x4:
// every trans result has >=3 slack insts) and s_nop 1 in the serial tanh(c).
__global__ __launch_bounds__(512, 2)
void lstm_seq_kernel(const int*   __restrict__ label,
                     const float* __restrict__ h0,     // (1, 4096, 128)
                     const float* __restrict__ W_ih,   // (512, 1)
                     const float* __restrict__ W_hh,   // (512, 128)
                     const float* __restrict__ b_ih,   // (512,)
                     const float* __restrict__ b_hh,   // (512,)
                     const float* __restrict__ W_lin,  // (1, 128)
                     const float* __restrict__ b_lin,  // (1,)
                     float*       __restrict__ out)    // (T, B, 1)
{
    const int tid   = threadIdx.x;
    const int batch = blockIdx.x;
    const int m     = tid >> 2;     // h element 0..127
    const int q     = tid & 3;      // K-quarter 0..3
    const int q8    = q * 8;

    const int ri = m, rf = m + 128, rg = m + 256, ro = m + 384;

    __shared__ float hbuf[2][160];  // ONLY LDS object

    const float4* W4 = (const float4*)W_hh;
    const float4* L4 = (const float4*)W_lin;

    // ---- C-side load + fold (used only for step 0) ----
    #define DECL_W(i) \
        float4 wi##i = W4[ri * 32 + q8 + (i)]; \
        float4 wf##i = W4[rf * 32 + q8 + (i)]; \
        float4 wg##i = W4[rg * 32 + q8 + (i)]; \
        float4 wo##i = W4[ro * 32 + q8 + (i)];
    REP8(DECL_W)

    const float wih_i = W_ih[ri], wih_f = W_ih[rf];
    const float wih_g = W_ih[rg], wih_o = W_ih[ro];
    const float blin  = b_lin[0];

    const float bi_ = b_ih[ri] + b_hh[ri] + wih_i * blin;
    const float bf_ = b_ih[rf] + b_hh[rf] + wih_f * blin;
    const float bg_ = b_ih[rg] + b_hh[rg] + wih_g * blin;
    const float bo_ = b_ih[ro] + b_hh[ro] + wih_o * blin;

    #define FOLD_W(i) { float4 lv = L4[q8 + (i)]; \
        wi##i.x = fmaf(wih_i, lv.x, wi##i.x); wi##i.y = fmaf(wih_i, lv.y, wi##i.y); \
        wi##i.z = fmaf(wih_i, lv.z, wi##i.z); wi##i.w = fmaf(wih_i, lv.w, wi##i.w); \
        wf##i.x = fmaf(wih_f, lv.x, wf##i.x); wf##i.y = fmaf(wih_f, lv.y, wf##i.y); \
        wf##i.z = fmaf(wih_f, lv.z, wf##i.z); wf##i.w = fmaf(wih_f, lv.w, wf##i.w); \
        wg##i.x = fmaf(wih_g, lv.x, wg##i.x); wg##i.y = fmaf(wih_g, lv.y, wg##i.y); \
        wg##i.z = fmaf(wih_g, lv.z, wg##i.z); wg##i.w = fmaf(wih_g, lv.w, wg##i.w); \
        wo##i.x = fmaf(wih_o, lv.x, wo##i.x); wo##i.y = fmaf(wih_o, lv.y, wo##i.y); \
        wo##i.z = fmaf(wih_o, lv.z, wo##i.z); wo##i.w = fmaf(wih_o, lv.w, wo##i.w); }
    REP8(FOLD_W)

    const int   lane = tid & 63;
    const int   ya0w = lane + ((lane >> 5) << 2);   // word of h[lane]
    const float wl_a = W_lin[lane];
    const float wl_b = W_lin[lane + 64];
    const int   hword = m + ((m >> 5) << 2);        // write word for element m

    // ---- init h into buf0 ----
    if (tid < HDIM) hbuf[0][tid + ((tid >> 5) << 2)] = h0[label[batch] * HDIM + tid];
    __syncthreads();

    // y_init (uniform across waves) for the t=0 bias correction
    float p0 = hbuf[0][ya0w] * wl_a + hbuf[0][ya0w + 72] * wl_b;
    #pragma unroll
    for (int off = 1; off < 64; off <<= 1) p0 += __shfl_xor(p0, off, 64);
    const float y0 = p0 + blin;

    const float cbi = bi_ - wih_i * y0;
    const float cbf = bf_ - wih_f * y0;
    const float cbg = bg_ - wih_g * y0;
    const float cbo = bo_ - wih_o * y0;

    // ---- step 0 in C: read buf0, write state s1 into buf1 ----
    const float4* hq0 = (const float4*)(&hbuf[0][0] + 36 * q);
    float ai = 0.f, af = 0.f, ag = 0.f, ao = 0.f;
    #define DOT4(i) { float4 hv = hq0[(i)]; \
        ai = fmaf(hv.x, wi##i.x, ai); ai = fmaf(hv.y, wi##i.y, ai); \
        ai = fmaf(hv.z, wi##i.z, ai); ai = fmaf(hv.w, wi##i.w, ai); \
        af = fmaf(hv.x, wf##i.x, af); af = fmaf(hv.y, wf##i.y, af); \
        af = fmaf(hv.z, wf##i.z, af); af = fmaf(hv.w, wf##i.w, af); \
        ag = fmaf(hv.x, wg##i.x, ag); ag = fmaf(hv.y, wg##i.y, ag); \
        ag = fmaf(hv.z, wg##i.z, ag); ag = fmaf(hv.w, wg##i.w, ag); \
        ao = fmaf(hv.x, wo##i.x, ao); ao = fmaf(hv.y, wo##i.y, ao); \
        ao = fmaf(hv.z, wo##i.z, ao); ao = fmaf(hv.w, wo##i.w, ao); }
    REP8(DOT4)
    ai += __shfl_xor(ai, 1, 64); af += __shfl_xor(af, 1, 64);
    ag += __shfl_xor(ag, 1, 64); ao += __shfl_xor(ao, 1, 64);
    ai += __shfl_xor(ai, 2, 64); af += __shfl_xor(af, 2, 64);
    ag += __shfl_xor(ag, 2, 64); ao += __shfl_xor(ao, 2, 64);
    const float iv0 = sigmoid_f(ai + cbi);
    const float fv0 = sigmoid_f(af + cbf);
    const float gv0 = tanh_f  (ag + cbg);
    const float ov0 = sigmoid_f(ao + cbo);
    float c = iv0 * gv0;                 // c_prev = 0
    const float hn0 = ov0 * tanh_f(c);
    if (q == 0) hbuf[1][hword] = hn0;
    __syncthreads();

    // ---- asm operand prep ----
    const unsigned ldsA = (unsigned)(unsigned long long)(&hbuf[0][0]);
    const unsigned vR0 = ldsA + 640u + 144u * (unsigned)q;       // read buf1
    const unsigned vW0 = ldsA + 4u * (unsigned)hword;            // write buf0
    const unsigned vY0 = ldsA + 640u + 4u * (unsigned)ya0w;      // y read buf1
    const unsigned vO0 = 4u * (unsigned)batch;                   // out[0] byte
    const unsigned offI = (unsigned)(ri * 512 + q * 128);
    const unsigned offF = (unsigned)(rf * 512 + q * 128);
    const unsigned offG = (unsigned)(rg * 512 + q * 128);
    const unsigned offO = (unsigned)(ro * 512 + q * 128);
    const unsigned offL = (unsigned)(q * 128);

    asm volatile(
        // ---------------- prologue: fixed-reg setup ----------------
        "v_mov_b32 v177, %[bi]\n\t"
        "v_mov_b32 v178, %[bf]\n\t"
        "v_mov_b32 v179, %[bg]\n\t"
        "v_mov_b32 v180, %[bo]\n\t"
        "v_mov_b32 v181, %[wla]\n\t"
        "v_mov_b32 v182, %[wlb]\n\t"
        "v_mov_b32 v185, %[blin]\n\t"
        "v_mov_b32 v168, %[c0]\n\t"
        "v_mov_b32 v172, %[vR]\n\t"
        "v_mov_b32 v173, %[vW]\n\t"
        "v_mov_b32 v174, %[vY]\n\t"
        "v_mov_b32 v176, %[vO]\n\t"
        "v_mov_b32 v175, 0xfffffd80\n\t"      // toggle = -640
        "v_and_b32 v186, 63, %[tid]\n\t"      // bpermute addr = 4*(lane^32)
        "v_xor_b32 v186, 32, v186\n\t"
        "v_lshlrev_b32 v186, 2, v186\n\t"
        "v_readfirstlane_b32 s25, %[tid]\n\t"
        "s_nop 4\n\t"
        // weights: 8x dwordx4 per gate into fixed quads
        "global_load_dwordx4 v[32:35], %[offI], %[whh] offset:0\n\t"
        "global_load_dwordx4 v[36:39], %[offI], %[whh] offset:16\n\t"
        "global_load_dwordx4 v[40:43], %[offI], %[whh] offset:32\n\t"
        "global_load_dwordx4 v[44:47], %[offI], %[whh] offset:48\n\t"
        "global_load_dwordx4 v[48:51], %[offI], %[whh] offset:64\n\t"
        "global_load_dwordx4 v[52:55], %[offI], %[whh] offset:80\n\t"
        "global_load_dwordx4 v[56:59], %[offI], %[whh] offset:96\n\t"
        "global_load_dwordx4 v[60:63], %[offI], %[whh] offset:112\n\t"
        "global_load_dwordx4 v[64:67], %[offF], %[whh] offset:0\n\t"
        "global_load_dwordx4 v[68:71], %[offF], %[whh] offset:16\n\t"
        "global_load_dwordx4 v[72:75], %[offF], %[whh] offset:32\n\t"
        "global_load_dwordx4 v[76:79], %[offF], %[whh] offset:48\n\t"
        "global_load_dwordx4 v[80:83], %[offF], %[whh] offset:64\n\t"
        "global_load_dwordx4 v[84:87], %[offF], %[whh] offset:80\n\t"
        "global_load_dwordx4 v[88:91], %[offF], %[whh] offset:96\n\t"
        "global_load_dwordx4 v[92:95], %[offF], %[whh] offset:112\n\t"
        "global_load_dwordx4 v[96:99], %[offG], %[whh] offset:0\n\t"
        "global_load_dwordx4 v[100:103], %[offG], %[whh] offset:16\n\t"
        "global_load_dwordx4 v[104:107], %[offG], %[whh] offset:32\n\t"
        "global_load_dwordx4 v[108:111], %[offG], %[whh] offset:48\n\t"
        "global_load_dwordx4 v[112:115], %[offG], %[whh] offset:64\n\t"
        "global_load_dwordx4 v[116:119], %[offG], %[whh] offset:80\n\t"
        "global_load_dwordx4 v[120:123], %[offG], %[whh] offset:96\n\t"
        "global_load_dwordx4 v[124:127], %[offG], %[whh] offset:112\n\t"
        "global_load_dwordx4 v[128:131], %[offO], %[whh] offset:0\n\t"
        "global_load_dwordx4 v[132:135], %[offO], %[whh] offset:16\n\t"
        "global_load_dwordx4 v[136:139], %[offO], %[whh] offset:32\n\t"
        "global_load_dwordx4 v[140:143], %[offO], %[whh] offset:48\n\t"
        "global_load_dwordx4 v[144:147], %[offO], %[whh] offset:64\n\t"
        "global_load_dwordx4 v[148:151], %[offO], %[whh] offset:80\n\t"
        "global_load_dwordx4 v[152:155], %[offO], %[whh] offset:96\n\t"
        "global_load_dwordx4 v[156:159], %[offO], %[whh] offset:112\n\t"
        "global_load_dwordx4 v[0:3],   %[offL], %[wlin] offset:0\n\t"
        "global_load_dwordx4 v[4:7],   %[offL], %[wlin] offset:16\n\t"
        "global_load_dwordx4 v[8:11],  %[offL], %[wlin] offset:32\n\t"
        "global_load_dwordx4 v[12:15], %[offL], %[wlin] offset:48\n\t"
        "global_load_dwordx4 v[16:19], %[offL], %[wlin] offset:64\n\t"
        "global_load_dwordx4 v[20:23], %[offL], %[wlin] offset:80\n\t"
        "global_load_dwordx4 v[24:27], %[offL], %[wlin] offset:96\n\t"
        "global_load_dwordx4 v[28:31], %[offL], %[wlin] offset:112\n\t"
        "s_waitcnt vmcnt(0)\n\t"
        // fold: W' = W + wih * W_lin
        ".set K_I, 0\n"
        ".rept 32\n"
        " v_fma_f32 v[32+K_I],  %[wihi], v[0+K_I], v[32+K_I]\n"
        " v_fma_f32 v[64+K_I],  %[wihf], v[0+K_I], v[64+K_I]\n"
        " v_fma_f32 v[96+K_I],  %[wihg], v[0+K_I], v[96+K_I]\n"
        " v_fma_f32 v[128+K_I], %[wiho], v[0+K_I], v[128+K_I]\n"
        " .set K_I, K_I+1\n"
        ".endr\n"
        "s_movk_i32 s24, 2047\n\t"
        // ---------------- main loop: t = 1 .. 2047 ----------------
        "1:\n\t"
        // y of previous h (wave 0 only), store out[t-1]
        "s_cmp_gt_u32 s25, 63\n\t"
        "s_cbranch_scc1 2f\n\t"
        "ds_read_b32 v183, v174\n\t"
        "ds_read_b32 v184, v174 offset:288\n\t"
        "s_waitcnt lgkmcnt(0)\n\t"
        "v_mul_f32 v183, v183, v181\n\t"
        "v_fma_f32 v183, v184, v182, v183\n\t"
        "ds_swizzle_b32 v184, v183 offset:0x041f\n\t"
        "s_waitcnt lgkmcnt(0)\n\t"
        "v_add_f32 v183, v183, v184\n\t"
        "ds_swizzle_b32 v184, v183 offset:0x081f\n\t"
        "s_waitcnt lgkmcnt(0)\n\t"
        "v_add_f32 v183, v183, v184\n\t"
        "ds_swizzle_b32 v184, v183 offset:0x101f\n\t"
        "s_waitcnt lgkmcnt(0)\n\t"
        "v_add_f32 v183, v183, v184\n\t"
        "ds_swizzle_b32 v184, v183 offset:0x201f\n\t"
        "s_waitcnt lgkmcnt(0)\n\t"
        "v_add_f32 v183, v183, v184\n\t"
        "ds_swizzle_b32 v184, v183 offset:0x401f\n\t"
        "s_waitcnt lgkmcnt(0)\n\t"
        "v_add_f32 v183, v183, v184\n\t"
        "ds_bpermute_b32 v184, v186, v183\n\t"
        "s_waitcnt lgkmcnt(0)\n\t"
        "v_add_f32 v183, v183, v184\n\t"
        "v_add_f32 v183, v183, v185\n\t"
        "s_mov_b64 s[22:23], exec\n\t"
        "s_mov_b64 exec, 1\n\t"
        "global_store_dword v176, v183, %[outp]\n\t"
        "s_mov_b64 exec, s[22:23]\n\t"
        "v_add_u32 v176, 0x400, v176\n\t"
        "2:\n\t"
        // h quarter: 8x b128 broadcast reads
        "ds_read_b128 v[0:3],   v172\n\t"
        "ds_read_b128 v[4:7],   v172 offset:16\n\t"
        "ds_read_b128 v[8:11],  v172 offset:32\n\t"
        "ds_read_b128 v[12:15], v172 offset:48\n\t"
        "ds_read_b128 v[16:19], v172 offset:64\n\t"
        "ds_read_b128 v[20:23], v172 offset:80\n\t"
        "ds_read_b128 v[24:27], v172 offset:96\n\t"
        "ds_read_b128 v[28:31], v172 offset:112\n\t"
        "v_mov_b32 v160, 0\n\t"
        "v_mov_b32 v161, 0\n\t"
        "v_mov_b32 v162, 0\n\t"
        "v_mov_b32 v163, 0\n\t"
        "s_waitcnt lgkmcnt(0)\n\t"
        // 128 FMAs, hard v-regs both sides
        ".set K_I, 0\n"
        ".rept 32\n"
        " v_fma_f32 v160, v[0+K_I], v[32+K_I],  v160\n"
        " v_fma_f32 v161, v[0+K_I], v[64+K_I],  v161\n"
        " v_fma_f32 v162, v[0+K_I], v[96+K_I],  v162\n"
        " v_fma_f32 v163, v[0+K_I], v[128+K_I], v163\n"
        " .set K_I, K_I+1\n"
        ".endr\n"
        // combine 4 K-quarters: xor1, xor2
        "ds_swizzle_b32 v164, v160 offset:0x041f\n\t"
        "ds_swizzle_b32 v165, v161 offset:0x041f\n\t"
        "ds_swizzle_b32 v166, v162 offset:0x041f\n\t"
        "ds_swizzle_b32 v167, v163 offset:0x041f\n\t"
        "s_waitcnt lgkmcnt(0)\n\t"
        "v_add_f32 v160, v160, v164\n\t"
        "v_add_f32 v161, v161, v165\n\t"
        "v_add_f32 v162, v162, v166\n\t"
        "v_add_f32 v163, v163, v167\n\t"
        "ds_swizzle_b32 v164, v160 offset:0x081f\n\t"
        "ds_swizzle_b32 v165, v161 offset:0x081f\n\t"
        "ds_swizzle_b32 v166, v162 offset:0x081f\n\t"
        "ds_swizzle_b32 v167, v163 offset:0x081f\n\t"
        "s_waitcnt lgkmcnt(0)\n\t"
        "v_add_f32 v160, v160, v164\n\t"
        "v_add_f32 v161, v161, v165\n\t"
        "v_add_f32 v162, v162, v166\n\t"
        "v_add_f32 v163, v163, v167\n\t"
        // + biases
        "v_add_f32 v160, v160, v177\n\t"
        "v_add_f32 v161, v161, v178\n\t"
        "v_add_f32 v162, v162, v179\n\t"
        "v_add_f32 v163, v163, v180\n\t"
        // ---- activations, TRANS-hazard-safe (interleaved, >=3 slack) ----
        // pre: v160=i, v161=f, v162=g, v163=o
        "v_mul_f32 v164, 0xbfb8aa3b, v160\n\t"   // -log2(e)*i
        "v_mul_f32 v165, 0xbfb8aa3b, v161\n\t"   // -log2(e)*f
        "v_mul_f32 v166, 0x4038aa3b, v162\n\t"   //  2log2(e)*g
        "v_mul_f32 v167, 0xbfb8aa3b, v163\n\t"   // -log2(e)*o
        "v_exp_f32 v164, v164\n\t"
        "v_exp_f32 v165, v165\n\t"
        "v_exp_f32 v166, v166\n\t"
        "v_exp_f32 v167, v167\n\t"
        "v_add_f32 v164, 1.0, v164\n\t"          // gap 3 from its exp
        "v_add_f32 v165, 1.0, v165\n\t"
        "v_add_f32 v166, 1.0, v166\n\t"
        "v_add_f32 v167, 1.0, v167\n\t"
        "v_rcp_f32 v166, v166\n\t"               // g-denom first
        "v_rcp_f32 v160, v164\n\t"               // i = sigmoid
        "v_rcp_f32 v161, v165\n\t"               // f = sigmoid
        "v_rcp_f32 v163, v167\n\t"               // o = sigmoid
        "v_fma_f32 v162, -2.0, v166, 1.0\n\t"    // g = tanh (gap 3 from rcp)
        "v_mul_f32 v170, v160, v162\n\t"         // i*g (gap 3 from rcp v160)
        "v_fma_f32 v168, v161, v168, v170\n\t"   // c = f*c + i*g (gap 3)
        // tanh(c) with explicit wait states
        "v_mul_f32 v170, 0x4038aa3b, v168\n\t"
        "v_exp_f32 v170, v170\n\t"
        "s_nop 1\n\t"
        "v_add_f32 v170, 1.0, v170\n\t"
        "v_rcp_f32 v170, v170\n\t"
        "s_nop 1\n\t"
        "v_fma_f32 v169, -2.0, v170, 1.0\n\t"
        "v_mul_f32 v169, v163, v169\n\t"         // hn = o * tanh(c)
        // publish h (4 lanes/group: same addr, same data)
        "ds_write_b32 v173, v169\n\t"
        // toggle dbuf addresses
        "v_add_u32 v172, v172, v175\n\t"
        "v_sub_u32 v173, v173, v175\n\t"
        "v_add_u32 v174, v174, v175\n\t"
        "v_sub_u32 v175, 0, v175\n\t"
        "s_waitcnt lgkmcnt(0)\n\t"
        "s_barrier\n\t"
        "s_add_i32 s24, s24, -1\n\t"
        "s_cmp_lg_u32 s24, 0\n\t"
        "s_cbranch_scc1 1b\n\t"
        :
        : [offI]"v"(offI), [offF]"v"(offF), [offG]"v"(offG), [offO]"v"(offO),
          [offL]"v"(offL), [whh]"s"(W_hh), [wlin]"s"(W_lin), [outp]"s"(out),
          [wihi]"v"(wih_i), [wihf]"v"(wih_f), [wihg]"v"(wih_g), [wiho]"v"(wih_o),
          [bi]"v"(bi_), [bf]"v"(bf_), [bg]"v"(bg_), [bo]"v"(bo_),
          [wla]"v"(wl_a), [wlb]"v"(wl_b), [blin]"v"(blin), [c0]"v"(c),
          [vR]"v"(vR0), [vW]"v"(vW0), [vY]"v"(vY0), [vO]"v"(vO0), [tid]"v"(tid)
        : "memory", "scc", "s20","s21","s22","s23","s24","s25",
          "v0","v1","v2","v3","v4","v5","v6","v7","v8","v9",
          "v10","v11","v12","v13","v14","v15","v16","v17","v18","v19",
          "v20","v21","v22","v23","v24","v25","v26","v27","v28","v29",
          "v30","v31","v32","v33","v34","v35","v36","v37","v38","v39",
          "v40","v41","v42","v43","v44","v45","v46","v47","v48","v49",
          "v50","v51","v52","v53","v54","v55","v56","v57","v58","v59",
          "v60","v61","v62","v63","v64","v65","v66","v67","v68","v69",
          "v70","v71","v72","v73","v74","v75","v76","v77","v78","v79",
          "v80","v81","v82","v83","v84","v85","v86","v87","v88","v89",
          "v90","v91","v92","v93","v94","v95","v96","v97","v98","v99",
          "v100","v101","v102","v103","v104","v105","v106","v107","v108","v109",
          "v110","v111","v112","v113","v114","v115","v116","v117","v118","v119",
          "v120","v121","v122","v123","v124","v125","v126","v127","v128","v129",
          "v130","v131","v132","v133","v134","v135","v136","v137","v138","v139",
          "v140","v141","v142","v143","v144","v145","v146","v147","v148","v149",
          "v150","v151","v152","v153","v154","v155","v156","v157","v158","v159",
          "v160","v161","v162","v163","v164","v165","v166","v167","v168","v169",
          "v170","v171","v172","v173","v174","v175","v176","v177","v178","v179",
          "v180","v181","v182","v183","v184","v185","v186");

    // ---- epilogue: y_final from hbuf[0] (iteration 2047 is odd -> buf0) ----
    float yv = hbuf[0][ya0w] * wl_a + hbuf[0][ya0w + 72] * wl_b;
    #pragma unroll
    for (int off = 1; off < 64; off <<= 1) yv += __shfl_xor(yv, off, 64);
    if (tid == 0) out[(T_STEPS - 1) * BATCH + batch] = yv + blin;
}

extern "C" void kernel_launch(void* const* d_in, const int* in_sizes, int n_in,
                              void* d_out, int out_size, void* d_ws, size_t ws_size,
                              hipStream_t stream) {
    // inputs: 0 input (unused), 1 label, 2 h0, 3 W_ih, 4 W_hh,
    //         5 b_ih, 6 b_hh, 7 W_lin, 8 b_lin
    const int*   label = (const int*)  d_in[1];
    const float* h0    = (const float*)d_in[2];
    const float* W_ih  = (const float*)d_in[3];
    const float* W_hh  = (const float*)d_in[4];
    const float* b_ih  = (const float*)d_in[5];
    const float* b_hh  = (const float*)d_in[6];
    const float* W_lin = (const float*)d_in[7];
    const float* b_lin = (const float*)d_in[8];
    float* out = (float*)d_out;

    lstm_seq_kernel<<<dim3(BATCH), dim3(512), 0, stream>>>(
        label, h0, W_ih, W_hh, b_ih, b_hh, W_lin, b_lin, out);
}

// Round 14
// 1488.495 us; speedup vs baseline: 1.1332x; 1.0270x over previous
//
#include <hip/hip_runtime.h>
#include <math.h>

// Problem constants: T=2048, B=256, H=128, IN_DIM=1, NUM_DATA=4096
#define T_STEPS 2048
#define BATCH   256
#define HDIM    128

__device__ __forceinline__ float fast_rcp(float x) { return __builtin_amdgcn_rcpf(x); }
__device__ __forceinline__ float sigmoid_f(float x) { return fast_rcp(1.0f + __expf(-x)); }
__device__ __forceinline__ float tanh_f(float x) {
    float e = __expf(2.0f * x);
    return 1.0f - 2.0f * fast_rcp(e + 1.0f);
}

#define REP8(M) M(0) M(1) M(2) M(3) M(4) M(5) M(6) M(7)

// R14 = R13 hand-asm loop (hard physical regs, trans-hazard-safe activations,
// absmax 0.0 @ 1529us) MINUS the per-step wave-0 y-reduction (7 serial LDS
// round-trips ~500-600cyc on the barrier-synced critical path) PLUS a
// deferred-y scheme:
//  * q==0 lanes write h_state_s into LDS history ring hist[s&127][m]
//    (slot stride 132 words; 66KB).
//  * every 128 steps, a FLUSH computes out[128k + j] = hist[j].W_lin + b_lin
//    for all 128 j in parallel (same (j,q) decomposition as the main loop:
//    8 ds_read_b128 + 32 FMA vs W_lin slice in v[188:219] + xor1/xor2
//    swizzle combine + masked store). 16 flushes ~ a few us total.
// Register map: h/hist v[0:31], wi v[32:63], wf v[64:95], wg v[96:127],
// wo v[128:159], acc v[160:163], tmp v[164:167], c v168, hn v169, tmp v170,
// j*1024 v171, rdaddr v172, wraddr v173, histwr v174, toggle v175,
// outbase v176, biases v[177:180], flushrd v184, blin v185, WL v[188:219].
// Store mask (q==0) in s[26:27]; loop counter s24 = t (1..2047).
__global__ __launch_bounds__(512, 2)
void lstm_seq_kernel(const int*   __restrict__ label,
                     const float* __restrict__ h0,     // (1, 4096, 128)
                     const float* __restrict__ W_ih,   // (512, 1)
                     const float* __restrict__ W_hh,   // (512, 128)
                     const float* __restrict__ b_ih,   // (512,)
                     const float* __restrict__ b_hh,   // (512,)
                     const float* __restrict__ W_lin,  // (1, 128)
                     const float* __restrict__ b_lin,  // (1,)
                     float*       __restrict__ out)    // (T, B, 1)
{
    const int tid   = threadIdx.x;
    const int batch = blockIdx.x;
    const int m     = tid >> 2;     // h element 0..127 (also flush t-slot j)
    const int q     = tid & 3;      // K-quarter 0..3
    const int q8    = q * 8;

    const int ri = m, rf = m + 128, rg = m + 256, ro = m + 384;

    __shared__ float hbuf[2][160];                                  // dbuf h
    __shared__ __attribute__((aligned(16))) float hist[128 * 132];  // y ring

    const float4* W4 = (const float4*)W_hh;
    const float4* L4 = (const float4*)W_lin;

    // ---- C-side load + fold (used only for step 0) ----
    #define DECL_W(i) \
        float4 wi##i = W4[ri * 32 + q8 + (i)]; \
        float4 wf##i = W4[rf * 32 + q8 + (i)]; \
        float4 wg##i = W4[rg * 32 + q8 + (i)]; \
        float4 wo##i = W4[ro * 32 + q8 + (i)];
    REP8(DECL_W)

    const float wih_i = W_ih[ri], wih_f = W_ih[rf];
    const float wih_g = W_ih[rg], wih_o = W_ih[ro];
    const float blin  = b_lin[0];

    const float bi_ = b_ih[ri] + b_hh[ri] + wih_i * blin;
    const float bf_ = b_ih[rf] + b_hh[rf] + wih_f * blin;
    const float bg_ = b_ih[rg] + b_hh[rg] + wih_g * blin;
    const float bo_ = b_ih[ro] + b_hh[ro] + wih_o * blin;

    #define FOLD_W(i) { float4 lv = L4[q8 + (i)]; \
        wi##i.x = fmaf(wih_i, lv.x, wi##i.x); wi##i.y = fmaf(wih_i, lv.y, wi##i.y); \
        wi##i.z = fmaf(wih_i, lv.z, wi##i.z); wi##i.w = fmaf(wih_i, lv.w, wi##i.w); \
        wf##i.x = fmaf(wih_f, lv.x, wf##i.x); wf##i.y = fmaf(wih_f, lv.y, wf##i.y); \
        wf##i.z = fmaf(wih_f, lv.z, wf##i.z); wf##i.w = fmaf(wih_f, lv.w, wf##i.w); \
        wg##i.x = fmaf(wih_g, lv.x, wg##i.x); wg##i.y = fmaf(wih_g, lv.y, wg##i.y); \
        wg##i.z = fmaf(wih_g, lv.z, wg##i.z); wg##i.w = fmaf(wih_g, lv.w, wg##i.w); \
        wo##i.x = fmaf(wih_o, lv.x, wo##i.x); wo##i.y = fmaf(wih_o, lv.y, wo##i.y); \
        wo##i.z = fmaf(wih_o, lv.z, wo##i.z); wo##i.w = fmaf(wih_o, lv.w, wo##i.w); }
    REP8(FOLD_W)

    const int   lane = tid & 63;
    const int   ya0w = lane + ((lane >> 5) << 2);   // word of h[lane] in hbuf
    const float wl_a = W_lin[lane];
    const float wl_b = W_lin[lane + 64];
    const int   hword = m + ((m >> 5) << 2);        // hbuf write word for m

    // ---- init h into buf0 ----
    if (tid < HDIM) hbuf[0][tid + ((tid >> 5) << 2)] = h0[label[batch] * HDIM + tid];
    __syncthreads();

    // y_init (uniform across waves) for the t=0 bias correction
    float p0 = hbuf[0][ya0w] * wl_a + hbuf[0][ya0w + 72] * wl_b;
    #pragma unroll
    for (int off = 1; off < 64; off <<= 1) p0 += __shfl_xor(p0, off, 64);
    const float y0 = p0 + blin;

    const float cbi = bi_ - wih_i * y0;
    const float cbf = bf_ - wih_f * y0;
    const float cbg = bg_ - wih_g * y0;
    const float cbo = bo_ - wih_o * y0;

    // ---- step 0 in C: read buf0, write state s=1 into buf1 AND hist[0] ----
    const float4* hq0 = (const float4*)(&hbuf[0][0] + 36 * q);
    float ai = 0.f, af = 0.f, ag = 0.f, ao = 0.f;
    #define DOT4(i) { float4 hv = hq0[(i)]; \
        ai = fmaf(hv.x, wi##i.x, ai); ai = fmaf(hv.y, wi##i.y, ai); \
        ai = fmaf(hv.z, wi##i.z, ai); ai = fmaf(hv.w, wi##i.w, ai); \
        af = fmaf(hv.x, wf##i.x, af); af = fmaf(hv.y, wf##i.y, af); \
        af = fmaf(hv.z, wf##i.z, af); af = fmaf(hv.w, wf##i.w, af); \
        ag = fmaf(hv.x, wg##i.x, ag); ag = fmaf(hv.y, wg##i.y, ag); \
        ag = fmaf(hv.z, wg##i.z, ag); ag = fmaf(hv.w, wg##i.w, ag); \
        ao = fmaf(hv.x, wo##i.x, ao); ao = fmaf(hv.y, wo##i.y, ao); \
        ao = fmaf(hv.z, wo##i.z, ao); ao = fmaf(hv.w, wo##i.w, ao); }
    REP8(DOT4)
    ai += __shfl_xor(ai, 1, 64); af += __shfl_xor(af, 1, 64);
    ag += __shfl_xor(ag, 1, 64); ao += __shfl_xor(ao, 1, 64);
    ai += __shfl_xor(ai, 2, 64); af += __shfl_xor(af, 2, 64);
    ag += __shfl_xor(ag, 2, 64); ao += __shfl_xor(ao, 2, 64);
    const float iv0 = sigmoid_f(ai + cbi);
    const float fv0 = sigmoid_f(af + cbf);
    const float gv0 = tanh_f  (ag + cbg);
    const float ov0 = sigmoid_f(ao + cbo);
    float c = iv0 * gv0;                 // c_prev = 0
    const float hn0 = ov0 * tanh_f(c);
    if (q == 0) { hbuf[1][hword] = hn0; hist[m] = hn0; }
    __syncthreads();

    // ---- asm operand prep ----
    const unsigned ldsA  = (unsigned)(unsigned long long)(&hbuf[0][0]);
    const unsigned histB = (unsigned)(unsigned long long)(&hist[0]);
    const unsigned vR0 = ldsA + 640u + 144u * (unsigned)q;   // read buf1
    const unsigned vW0 = ldsA + 4u * (unsigned)hword;        // write buf0
    const unsigned hW0 = histB + 528u + 4u * (unsigned)m;    // hist slot1,word m
    const unsigned fR0 = histB + 528u * (unsigned)m + 128u * (unsigned)q;
    const unsigned jO0 = 1024u * (unsigned)m;                // out offset j*1024
    const unsigned vO0 = 4u * (unsigned)batch;               // out[0] byte
    const unsigned offI = (unsigned)(ri * 512 + q * 128);
    const unsigned offF = (unsigned)(rf * 512 + q * 128);
    const unsigned offG = (unsigned)(rg * 512 + q * 128);
    const unsigned offO = (unsigned)(ro * 512 + q * 128);
    const unsigned offL = (unsigned)(q * 128);

    asm volatile(
        // ---------------- prologue: fixed-reg setup ----------------
        "v_mov_b32 v177, %[bi]\n\t"
        "v_mov_b32 v178, %[bf]\n\t"
        "v_mov_b32 v179, %[bg]\n\t"
        "v_mov_b32 v180, %[bo]\n\t"
        "v_mov_b32 v185, %[blin]\n\t"
        "v_mov_b32 v168, %[c0]\n\t"
        "v_mov_b32 v172, %[vR]\n\t"
        "v_mov_b32 v173, %[vW]\n\t"
        "v_mov_b32 v174, %[hW]\n\t"
        "v_mov_b32 v184, %[fR]\n\t"
        "v_mov_b32 v171, %[jO]\n\t"
        "v_mov_b32 v176, %[vO]\n\t"
        "v_mov_b32 v175, 0xfffffd80\n\t"      // hbuf toggle = -640
        // q==0 store mask -> s[26:27]
        "v_and_b32 v170, 3, %[tid]\n\t"
        "v_cmp_eq_u32 vcc, 0, v170\n\t"
        "s_nop 4\n\t"
        "s_mov_b64 s[26:27], vcc\n\t"
        // weights: 8x dwordx4 per gate into fixed quads
        "global_load_dwordx4 v[32:35], %[offI], %[whh] offset:0\n\t"
        "global_load_dwordx4 v[36:39], %[offI], %[whh] offset:16\n\t"
        "global_load_dwordx4 v[40:43], %[offI], %[whh] offset:32\n\t"
        "global_load_dwordx4 v[44:47], %[offI], %[whh] offset:48\n\t"
        "global_load_dwordx4 v[48:51], %[offI], %[whh] offset:64\n\t"
        "global_load_dwordx4 v[52:55], %[offI], %[whh] offset:80\n\t"
        "global_load_dwordx4 v[56:59], %[offI], %[whh] offset:96\n\t"
        "global_load_dwordx4 v[60:63], %[offI], %[whh] offset:112\n\t"
        "global_load_dwordx4 v[64:67], %[offF], %[whh] offset:0\n\t"
        "global_load_dwordx4 v[68:71], %[offF], %[whh] offset:16\n\t"
        "global_load_dwordx4 v[72:75], %[offF], %[whh] offset:32\n\t"
        "global_load_dwordx4 v[76:79], %[offF], %[whh] offset:48\n\t"
        "global_load_dwordx4 v[80:83], %[offF], %[whh] offset:64\n\t"
        "global_load_dwordx4 v[84:87], %[offF], %[whh] offset:80\n\t"
        "global_load_dwordx4 v[88:91], %[offF], %[whh] offset:96\n\t"
        "global_load_dwordx4 v[92:95], %[offF], %[whh] offset:112\n\t"
        "global_load_dwordx4 v[96:99], %[offG], %[whh] offset:0\n\t"
        "global_load_dwordx4 v[100:103], %[offG], %[whh] offset:16\n\t"
        "global_load_dwordx4 v[104:107], %[offG], %[whh] offset:32\n\t"
        "global_load_dwordx4 v[108:111], %[offG], %[whh] offset:48\n\t"
        "global_load_dwordx4 v[112:115], %[offG], %[whh] offset:64\n\t"
        "global_load_dwordx4 v[116:119], %[offG], %[whh] offset:80\n\t"
        "global_load_dwordx4 v[120:123], %[offG], %[whh] offset:96\n\t"
        "global_load_dwordx4 v[124:127], %[offG], %[whh] offset:112\n\t"
        "global_load_dwordx4 v[128:131], %[offO], %[whh] offset:0\n\t"
        "global_load_dwordx4 v[132:135], %[offO], %[whh] offset:16\n\t"
        "global_load_dwordx4 v[136:139], %[offO], %[whh] offset:32\n\t"
        "global_load_dwordx4 v[140:143], %[offO], %[whh] offset:48\n\t"
        "global_load_dwordx4 v[144:147], %[offO], %[whh] offset:64\n\t"
        "global_load_dwordx4 v[148:151], %[offO], %[whh] offset:80\n\t"
        "global_load_dwordx4 v[152:155], %[offO], %[whh] offset:96\n\t"
        "global_load_dwordx4 v[156:159], %[offO], %[whh] offset:112\n\t"
        // W_lin quarter-slice -> persistent v[188:219]
        "global_load_dwordx4 v[188:191], %[offL], %[wlin] offset:0\n\t"
        "global_load_dwordx4 v[192:195], %[offL], %[wlin] offset:16\n\t"
        "global_load_dwordx4 v[196:199], %[offL], %[wlin] offset:32\n\t"
        "global_load_dwordx4 v[200:203], %[offL], %[wlin] offset:48\n\t"
        "global_load_dwordx4 v[204:207], %[offL], %[wlin] offset:64\n\t"
        "global_load_dwordx4 v[208:211], %[offL], %[wlin] offset:80\n\t"
        "global_load_dwordx4 v[212:215], %[offL], %[wlin] offset:96\n\t"
        "global_load_dwordx4 v[216:219], %[offL], %[wlin] offset:112\n\t"
        "s_waitcnt vmcnt(0)\n\t"
        // fold: W' = W + wih * W_lin
        ".set K_I, 0\n"
        ".rept 32\n"
        " v_fma_f32 v[32+K_I],  %[wihi], v[188+K_I], v[32+K_I]\n"
        " v_fma_f32 v[64+K_I],  %[wihf], v[188+K_I], v[64+K_I]\n"
        " v_fma_f32 v[96+K_I],  %[wihg], v[188+K_I], v[96+K_I]\n"
        " v_fma_f32 v[128+K_I], %[wiho], v[188+K_I], v[128+K_I]\n"
        " .set K_I, K_I+1\n"
        ".endr\n"
        "s_movk_i32 s24, 1\n\t"
        // ---------------- main loop: t = 1 .. 2047 ----------------
        "1:\n\t"
        // h quarter: 8x b128 broadcast reads
        "ds_read_b128 v[0:3],   v172\n\t"
        "ds_read_b128 v[4:7],   v172 offset:16\n\t"
        "ds_read_b128 v[8:11],  v172 offset:32\n\t"
        "ds_read_b128 v[12:15], v172 offset:48\n\t"
        "ds_read_b128 v[16:19], v172 offset:64\n\t"
        "ds_read_b128 v[20:23], v172 offset:80\n\t"
        "ds_read_b128 v[24:27], v172 offset:96\n\t"
        "ds_read_b128 v[28:31], v172 offset:112\n\t"
        "v_mov_b32 v160, 0\n\t"
        "v_mov_b32 v161, 0\n\t"
        "v_mov_b32 v162, 0\n\t"
        "v_mov_b32 v163, 0\n\t"
        "s_waitcnt lgkmcnt(0)\n\t"
        // 128 FMAs, hard v-regs both sides
        ".set K_I, 0\n"
        ".rept 32\n"
        " v_fma_f32 v160, v[0+K_I], v[32+K_I],  v160\n"
        " v_fma_f32 v161, v[0+K_I], v[64+K_I],  v161\n"
        " v_fma_f32 v162, v[0+K_I], v[96+K_I],  v162\n"
        " v_fma_f32 v163, v[0+K_I], v[128+K_I], v163\n"
        " .set K_I, K_I+1\n"
        ".endr\n"
        // combine 4 K-quarters: xor1, xor2
        "ds_swizzle_b32 v164, v160 offset:0x041f\n\t"
        "ds_swizzle_b32 v165, v161 offset:0x041f\n\t"
        "ds_swizzle_b32 v166, v162 offset:0x041f\n\t"
        "ds_swizzle_b32 v167, v163 offset:0x041f\n\t"
        "s_waitcnt lgkmcnt(0)\n\t"
        "v_add_f32 v160, v160, v164\n\t"
        "v_add_f32 v161, v161, v165\n\t"
        "v_add_f32 v162, v162, v166\n\t"
        "v_add_f32 v163, v163, v167\n\t"
        "ds_swizzle_b32 v164, v160 offset:0x081f\n\t"
        "ds_swizzle_b32 v165, v161 offset:0x081f\n\t"
        "ds_swizzle_b32 v166, v162 offset:0x081f\n\t"
        "ds_swizzle_b32 v167, v163 offset:0x081f\n\t"
        "s_waitcnt lgkmcnt(0)\n\t"
        "v_add_f32 v160, v160, v164\n\t"
        "v_add_f32 v161, v161, v165\n\t"
        "v_add_f32 v162, v162, v166\n\t"
        "v_add_f32 v163, v163, v167\n\t"
        // + biases
        "v_add_f32 v160, v160, v177\n\t"
        "v_add_f32 v161, v161, v178\n\t"
        "v_add_f32 v162, v162, v179\n\t"
        "v_add_f32 v163, v163, v180\n\t"
        // ---- activations, TRANS-hazard-safe (interleaved, >=3 slack) ----
        "v_mul_f32 v164, 0xbfb8aa3b, v160\n\t"   // -log2(e)*i
        "v_mul_f32 v165, 0xbfb8aa3b, v161\n\t"   // -log2(e)*f
        "v_mul_f32 v166, 0x4038aa3b, v162\n\t"   //  2log2(e)*g
        "v_mul_f32 v167, 0xbfb8aa3b, v163\n\t"   // -log2(e)*o
        "v_exp_f32 v164, v164\n\t"
        "v_exp_f32 v165, v165\n\t"
        "v_exp_f32 v166, v166\n\t"
        "v_exp_f32 v167, v167\n\t"
        "v_add_f32 v164, 1.0, v164\n\t"
        "v_add_f32 v165, 1.0, v165\n\t"
        "v_add_f32 v166, 1.0, v166\n\t"
        "v_add_f32 v167, 1.0, v167\n\t"
        "v_rcp_f32 v166, v166\n\t"               // g-denom first
        "v_rcp_f32 v160, v164\n\t"               // i = sigmoid
        "v_rcp_f32 v161, v165\n\t"               // f = sigmoid
        "v_rcp_f32 v163, v167\n\t"               // o = sigmoid
        "v_fma_f32 v162, -2.0, v166, 1.0\n\t"    // g = tanh
        "v_mul_f32 v170, v160, v162\n\t"         // i*g
        "v_fma_f32 v168, v161, v168, v170\n\t"   // c = f*c + i*g
        // tanh(c) with explicit wait states
        "v_mul_f32 v170, 0x4038aa3b, v168\n\t"
        "v_exp_f32 v170, v170\n\t"
        "s_nop 1\n\t"
        "v_add_f32 v170, 1.0, v170\n\t"
        "v_rcp_f32 v170, v170\n\t"
        "s_nop 1\n\t"
        "v_fma_f32 v169, -2.0, v170, 1.0\n\t"
        "v_mul_f32 v169, v163, v169\n\t"         // hn = o * tanh(c)
        // publish h (q==0 lanes: hbuf dbuf + history ring)
        "s_mov_b64 s[22:23], exec\n\t"
        "s_mov_b64 exec, s[26:27]\n\t"
        "ds_write_b32 v173, v169\n\t"
        "ds_write_b32 v174, v169\n\t"
        "s_mov_b64 exec, s[22:23]\n\t"
        // advance addresses
        "v_add_u32 v172, v172, v175\n\t"
        "v_sub_u32 v173, v173, v175\n\t"
        "v_sub_u32 v175, 0, v175\n\t"
        "v_add_u32 v174, 0x210, v174\n\t"        // hist += 528
        "s_waitcnt lgkmcnt(0)\n\t"
        "s_barrier\n\t"
        // ---- flush every 128 steps: out[128k + j] = hist[j].WL + blin ----
        "s_and_b32 s20, s24, 127\n\t"
        "s_cmp_lg_u32 s20, 127\n\t"
        "s_cbranch_scc1 3f\n\t"
        "v_add_u32 v174, 0xfffef800, v174\n\t"   // hist write base wrap -67584
        "ds_read_b128 v[0:3],   v184\n\t"
        "ds_read_b128 v[4:7],   v184 offset:16\n\t"
        "ds_read_b128 v[8:11],  v184 offset:32\n\t"
        "ds_read_b128 v[12:15], v184 offset:48\n\t"
        "ds_read_b128 v[16:19], v184 offset:64\n\t"
        "ds_read_b128 v[20:23], v184 offset:80\n\t"
        "ds_read_b128 v[24:27], v184 offset:96\n\t"
        "ds_read_b128 v[28:31], v184 offset:112\n\t"
        "v_mov_b32 v164, 0\n\t"
        "s_waitcnt lgkmcnt(0)\n\t"
        ".set K_I, 0\n"
        ".rept 32\n"
        " v_fma_f32 v164, v[0+K_I], v[188+K_I], v164\n"
        " .set K_I, K_I+1\n"
        ".endr\n"
        "ds_swizzle_b32 v165, v164 offset:0x041f\n\t"
        "s_waitcnt lgkmcnt(0)\n\t"
        "v_add_f32 v164, v164, v165\n\t"
        "ds_swizzle_b32 v165, v164 offset:0x081f\n\t"
        "s_waitcnt lgkmcnt(0)\n\t"
        "v_add_f32 v164, v164, v165\n\t"
        "v_add_f32 v164, v164, v185\n\t"         // + b_lin
        "v_add_u32 v170, v176, v171\n\t"         // out byte = base + j*1024
        "s_mov_b64 s[22:23], exec\n\t"
        "s_mov_b64 exec, s[26:27]\n\t"
        "global_store_dword v170, v164, %[outp]\n\t"
        "s_mov_b64 exec, s[22:23]\n\t"
        "v_add_u32 v176, 0x20000, v176\n\t"      // out base += 128*256*4
        "s_barrier\n\t"                           // protect hist vs next iter
        "3:\n\t"
        "s_add_i32 s24, s24, 1\n\t"
        "s_cmp_lt_i32 s24, 2048\n\t"
        "s_cbranch_scc1 1b\n\t"
        :
        : [offI]"v"(offI), [offF]"v"(offF), [offG]"v"(offG), [offO]"v"(offO),
          [offL]"v"(offL), [whh]"s"(W_hh), [wlin]"s"(W_lin), [outp]"s"(out),
          [wihi]"v"(wih_i), [wihf]"v"(wih_f), [wihg]"v"(wih_g), [wiho]"v"(wih_o),
          [bi]"v"(bi_), [bf]"v"(bf_), [bg]"v"(bg_), [bo]"v"(bo_),
          [blin]"v"(blin), [c0]"v"(c),
          [vR]"v"(vR0), [vW]"v"(vW0), [hW]"v"(hW0), [fR]"v"(fR0),
          [jO]"v"(jO0), [vO]"v"(vO0), [tid]"v"(tid)
        : "memory", "scc", "vcc", "s20","s21","s22","s23","s24","s25","s26","s27",
          "v0","v1","v2","v3","v4","v5","v6","v7","v8","v9",
          "v10","v11","v12","v13","v14","v15","v16","v17","v18","v19",
          "v20","v21","v22","v23","v24","v25","v26","v27","v28","v29",
          "v30","v31","v32","v33","v34","v35","v36","v37","v38","v39",
          "v40","v41","v42","v43","v44","v45","v46","v47","v48","v49",
          "v50","v51","v52","v53","v54","v55","v56","v57","v58","v59",
          "v60","v61","v62","v63","v64","v65","v66","v67","v68","v69",
          "v70","v71","v72","v73","v74","v75","v76","v77","v78","v79",
          "v80","v81","v82","v83","v84","v85","v86","v87","v88","v89",
          "v90","v91","v92","v93","v94","v95","v96","v97","v98","v99",
          "v100","v101","v102","v103","v104","v105","v106","v107","v108","v109",
          "v110","v111","v112","v113","v114","v115","v116","v117","v118","v119",
          "v120","v121","v122","v123","v124","v125","v126","v127","v128","v129",
          "v130","v131","v132","v133","v134","v135","v136","v137","v138","v139",
          "v140","v141","v142","v143","v144","v145","v146","v147","v148","v149",
          "v150","v151","v152","v153","v154","v155","v156","v157","v158","v159",
          "v160","v161","v162","v163","v164","v165","v166","v167","v168","v169",
          "v170","v171","v172","v173","v174","v175","v176","v177","v178","v179",
          "v180","v181","v182","v183","v184","v185","v186","v187","v188","v189",
          "v190","v191","v192","v193","v194","v195","v196","v197","v198","v199",
          "v200","v201","v202","v203","v204","v205","v206","v207","v208","v209",
          "v210","v211","v212","v213","v214","v215","v216","v217","v218","v219");
    // no C epilogue: flush k=15 covers out[1920..2047]
}

extern "C" void kernel_launch(void* const* d_in, const int* in_sizes, int n_in,
                              void* d_out, int out_size, void* d_ws, size_t ws_size,
                              hipStream_t stream) {
    // inputs: 0 input (unused), 1 label, 2 h0, 3 W_ih, 4 W_hh,
    //         5 b_ih, 6 b_hh, 7 W_lin, 8 b_lin
    const int*   label = (const int*)  d_in[1];
    const float* h0    = (const float*)d_in[2];
    const float* W_ih  = (const float*)d_in[3];
    const float* W_hh  = (const float*)d_in[4];
    const float* b_ih  = (const float*)d_in[5];
    const float* b_hh  = (const float*)d_in[6];
    const float* W_lin = (const float*)d_in[7];
    const float* b_lin = (const float*)d_in[8];
    float* out = (float*)d_out;

    lstm_seq_kernel<<<dim3(BATCH), dim3(512), 0, stream>>>(
        label, h0, W_ih, W_hh, b_ih, b_hh, W_lin, b_lin, out);
}

// Round 15
// 1300.881 us; speedup vs baseline: 1.2967x; 1.1442x over previous
//
#include <hip/hip_runtime.h>
#include <math.h>

// Problem constants: T=2048, B=256, H=128, IN_DIM=1, NUM_DATA=4096
#define T_STEPS 2048
#define BATCH   256
#define HDIM    128

__device__ __forceinline__ float fast_rcp(float x) { return __builtin_amdgcn_rcpf(x); }
__device__ __forceinline__ float sigmoid_f(float x) { return fast_rcp(1.0f + __expf(-x)); }
__device__ __forceinline__ float tanh_f(float x) {
    float e = __expf(2.0f * x);
    return 1.0f - 2.0f * fast_rcp(e + 1.0f);
}

#define REP8(M) M(0) M(1) M(2) M(3) M(4) M(5) M(6) M(7)

// R15 = R14 (hand-asm loop + LDS history ring + deferred flush, 1488us)
// with the quarter-combine moved from the LDS pipe to the VALU pipe:
//  * ds_swizzle xor1/xor2 (2 serialized LDS round-trips ~240cyc on the
//    barrier-locked critical path + 64 LDS ops/CU/step) -> v_add_f32_dpp
//    quad_perm:[1,0,3,2] / [2,3,0,1] (VALU, ~4cyc). DPP hazard (VALU write
//    -> DPP read needs 2 wait states) covered by 4-reg interleave (>=3
//    intervening) and s_nop 1 in the flush (gap 0 there).
//  * accumulators start as v_mul (first K float) - drops 4 zero-movs.
//  * staggered s_waitcnt lgkmcnt(6/4/2/0): FMA quads 0-1 run while reads
//    2-7 are still in flight (~60-100cyc of post-barrier latency hidden).
// Register map unchanged: h v[0:31], wi v[32:63], wf v[64:95], wg v[96:127],
// wo v[128:159], acc v[160:163], tmp v164-167, c v168, hn v169, tmp v170,
// j*1024 v171, rdaddr v172, wraddr v173, histwr v174, toggle v175,
// outbase v176, biases v[177:180], flushrd v184, blin v185, WL v[188:219].
__global__ __launch_bounds__(512, 2)
void lstm_seq_kernel(const int*   __restrict__ label,
                     const float* __restrict__ h0,     // (1, 4096, 128)
                     const float* __restrict__ W_ih,   // (512, 1)
                     const float* __restrict__ W_hh,   // (512, 128)
                     const float* __restrict__ b_ih,   // (512,)
                     const float* __restrict__ b_hh,   // (512,)
                     const float* __restrict__ W_lin,  // (1, 128)
                     const float* __restrict__ b_lin,  // (1,)
                     float*       __restrict__ out)    // (T, B, 1)
{
    const int tid   = threadIdx.x;
    const int batch = blockIdx.x;
    const int m     = tid >> 2;     // h element 0..127 (also flush t-slot j)
    const int q     = tid & 3;      // K-quarter 0..3
    const int q8    = q * 8;

    const int ri = m, rf = m + 128, rg = m + 256, ro = m + 384;

    __shared__ float hbuf[2][160];                                  // dbuf h
    __shared__ __attribute__((aligned(16))) float hist[128 * 132];  // y ring

    const float4* W4 = (const float4*)W_hh;
    const float4* L4 = (const float4*)W_lin;

    // ---- C-side load + fold (used only for step 0) ----
    #define DECL_W(i) \
        float4 wi##i = W4[ri * 32 + q8 + (i)]; \
        float4 wf##i = W4[rf * 32 + q8 + (i)]; \
        float4 wg##i = W4[rg * 32 + q8 + (i)]; \
        float4 wo##i = W4[ro * 32 + q8 + (i)];
    REP8(DECL_W)

    const float wih_i = W_ih[ri], wih_f = W_ih[rf];
    const float wih_g = W_ih[rg], wih_o = W_ih[ro];
    const float blin  = b_lin[0];

    const float bi_ = b_ih[ri] + b_hh[ri] + wih_i * blin;
    const float bf_ = b_ih[rf] + b_hh[rf] + wih_f * blin;
    const float bg_ = b_ih[rg] + b_hh[rg] + wih_g * blin;
    const float bo_ = b_ih[ro] + b_hh[ro] + wih_o * blin;

    #define FOLD_W(i) { float4 lv = L4[q8 + (i)]; \
        wi##i.x = fmaf(wih_i, lv.x, wi##i.x); wi##i.y = fmaf(wih_i, lv.y, wi##i.y); \
        wi##i.z = fmaf(wih_i, lv.z, wi##i.z); wi##i.w = fmaf(wih_i, lv.w, wi##i.w); \
        wf##i.x = fmaf(wih_f, lv.x, wf##i.x); wf##i.y = fmaf(wih_f, lv.y, wf##i.y); \
        wf##i.z = fmaf(wih_f, lv.z, wf##i.z); wf##i.w = fmaf(wih_f, lv.w, wf##i.w); \
        wg##i.x = fmaf(wih_g, lv.x, wg##i.x); wg##i.y = fmaf(wih_g, lv.y, wg##i.y); \
        wg##i.z = fmaf(wih_g, lv.z, wg##i.z); wg##i.w = fmaf(wih_g, lv.w, wg##i.w); \
        wo##i.x = fmaf(wih_o, lv.x, wo##i.x); wo##i.y = fmaf(wih_o, lv.y, wo##i.y); \
        wo##i.z = fmaf(wih_o, lv.z, wo##i.z); wo##i.w = fmaf(wih_o, lv.w, wo##i.w); }
    REP8(FOLD_W)

    const int   lane = tid & 63;
    const int   ya0w = lane + ((lane >> 5) << 2);   // word of h[lane] in hbuf
    const float wl_a = W_lin[lane];
    const float wl_b = W_lin[lane + 64];
    const int   hword = m + ((m >> 5) << 2);        // hbuf write word for m

    // ---- init h into buf0 ----
    if (tid < HDIM) hbuf[0][tid + ((tid >> 5) << 2)] = h0[label[batch] * HDIM + tid];
    __syncthreads();

    // y_init (uniform across waves) for the t=0 bias correction
    float p0 = hbuf[0][ya0w] * wl_a + hbuf[0][ya0w + 72] * wl_b;
    #pragma unroll
    for (int off = 1; off < 64; off <<= 1) p0 += __shfl_xor(p0, off, 64);
    const float y0 = p0 + blin;

    const float cbi = bi_ - wih_i * y0;
    const float cbf = bf_ - wih_f * y0;
    const float cbg = bg_ - wih_g * y0;
    const float cbo = bo_ - wih_o * y0;

    // ---- step 0 in C: read buf0, write state s=1 into buf1 AND hist[0] ----
    const float4* hq0 = (const float4*)(&hbuf[0][0] + 36 * q);
    float ai = 0.f, af = 0.f, ag = 0.f, ao = 0.f;
    #define DOT4(i) { float4 hv = hq0[(i)]; \
        ai = fmaf(hv.x, wi##i.x, ai); ai = fmaf(hv.y, wi##i.y, ai); \
        ai = fmaf(hv.z, wi##i.z, ai); ai = fmaf(hv.w, wi##i.w, ai); \
        af = fmaf(hv.x, wf##i.x, af); af = fmaf(hv.y, wf##i.y, af); \
        af = fmaf(hv.z, wf##i.z, af); af = fmaf(hv.w, wf##i.w, af); \
        ag = fmaf(hv.x, wg##i.x, ag); ag = fmaf(hv.y, wg##i.y, ag); \
        ag = fmaf(hv.z, wg##i.z, ag); ag = fmaf(hv.w, wg##i.w, ag); \
        ao = fmaf(hv.x, wo##i.x, ao); ao = fmaf(hv.y, wo##i.y, ao); \
        ao = fmaf(hv.z, wo##i.z, ao); ao = fmaf(hv.w, wo##i.w, ao); }
    REP8(DOT4)
    ai += __shfl_xor(ai, 1, 64); af += __shfl_xor(af, 1, 64);
    ag += __shfl_xor(ag, 1, 64); ao += __shfl_xor(ao, 1, 64);
    ai += __shfl_xor(ai, 2, 64); af += __shfl_xor(af, 2, 64);
    ag += __shfl_xor(ag, 2, 64); ao += __shfl_xor(ao, 2, 64);
    const float iv0 = sigmoid_f(ai + cbi);
    const float fv0 = sigmoid_f(af + cbf);
    const float gv0 = tanh_f  (ag + cbg);
    const float ov0 = sigmoid_f(ao + cbo);
    float c = iv0 * gv0;                 // c_prev = 0
    const float hn0 = ov0 * tanh_f(c);
    if (q == 0) { hbuf[1][hword] = hn0; hist[m] = hn0; }
    __syncthreads();

    // ---- asm operand prep ----
    const unsigned ldsA  = (unsigned)(unsigned long long)(&hbuf[0][0]);
    const unsigned histB = (unsigned)(unsigned long long)(&hist[0]);
    const unsigned vR0 = ldsA + 640u + 144u * (unsigned)q;   // read buf1
    const unsigned vW0 = ldsA + 4u * (unsigned)hword;        // write buf0
    const unsigned hW0 = histB + 528u + 4u * (unsigned)m;    // hist slot1,word m
    const unsigned fR0 = histB + 528u * (unsigned)m + 128u * (unsigned)q;
    const unsigned jO0 = 1024u * (unsigned)m;                // out offset j*1024
    const unsigned vO0 = 4u * (unsigned)batch;               // out[0] byte
    const unsigned offI = (unsigned)(ri * 512 + q * 128);
    const unsigned offF = (unsigned)(rf * 512 + q * 128);
    const unsigned offG = (unsigned)(rg * 512 + q * 128);
    const unsigned offO = (unsigned)(ro * 512 + q * 128);
    const unsigned offL = (unsigned)(q * 128);

    asm volatile(
        // ---------------- prologue: fixed-reg setup ----------------
        "v_mov_b32 v177, %[bi]\n\t"
        "v_mov_b32 v178, %[bf]\n\t"
        "v_mov_b32 v179, %[bg]\n\t"
        "v_mov_b32 v180, %[bo]\n\t"
        "v_mov_b32 v185, %[blin]\n\t"
        "v_mov_b32 v168, %[c0]\n\t"
        "v_mov_b32 v172, %[vR]\n\t"
        "v_mov_b32 v173, %[vW]\n\t"
        "v_mov_b32 v174, %[hW]\n\t"
        "v_mov_b32 v184, %[fR]\n\t"
        "v_mov_b32 v171, %[jO]\n\t"
        "v_mov_b32 v176, %[vO]\n\t"
        "v_mov_b32 v175, 0xfffffd80\n\t"      // hbuf toggle = -640
        // q==0 store mask -> s[26:27]
        "v_and_b32 v170, 3, %[tid]\n\t"
        "v_cmp_eq_u32 vcc, 0, v170\n\t"
        "s_nop 4\n\t"
        "s_mov_b64 s[26:27], vcc\n\t"
        // weights: 8x dwordx4 per gate into fixed quads
        "global_load_dwordx4 v[32:35], %[offI], %[whh] offset:0\n\t"
        "global_load_dwordx4 v[36:39], %[offI], %[whh] offset:16\n\t"
        "global_load_dwordx4 v[40:43], %[offI], %[whh] offset:32\n\t"
        "global_load_dwordx4 v[44:47], %[offI], %[whh] offset:48\n\t"
        "global_load_dwordx4 v[48:51], %[offI], %[whh] offset:64\n\t"
        "global_load_dwordx4 v[52:55], %[offI], %[whh] offset:80\n\t"
        "global_load_dwordx4 v[56:59], %[offI], %[whh] offset:96\n\t"
        "global_load_dwordx4 v[60:63], %[offI], %[whh] offset:112\n\t"
        "global_load_dwordx4 v[64:67], %[offF], %[whh] offset:0\n\t"
        "global_load_dwordx4 v[68:71], %[offF], %[whh] offset:16\n\t"
        "global_load_dwordx4 v[72:75], %[offF], %[whh] offset:32\n\t"
        "global_load_dwordx4 v[76:79], %[offF], %[whh] offset:48\n\t"
        "global_load_dwordx4 v[80:83], %[offF], %[whh] offset:64\n\t"
        "global_load_dwordx4 v[84:87], %[offF], %[whh] offset:80\n\t"
        "global_load_dwordx4 v[88:91], %[offF], %[whh] offset:96\n\t"
        "global_load_dwordx4 v[92:95], %[offF], %[whh] offset:112\n\t"
        "global_load_dwordx4 v[96:99], %[offG], %[whh] offset:0\n\t"
        "global_load_dwordx4 v[100:103], %[offG], %[whh] offset:16\n\t"
        "global_load_dwordx4 v[104:107], %[offG], %[whh] offset:32\n\t"
        "global_load_dwordx4 v[108:111], %[offG], %[whh] offset:48\n\t"
        "global_load_dwordx4 v[112:115], %[offG], %[whh] offset:64\n\t"
        "global_load_dwordx4 v[116:119], %[offG], %[whh] offset:80\n\t"
        "global_load_dwordx4 v[120:123], %[offG], %[whh] offset:96\n\t"
        "global_load_dwordx4 v[124:127], %[offG], %[whh] offset:112\n\t"
        "global_load_dwordx4 v[128:131], %[offO], %[whh] offset:0\n\t"
        "global_load_dwordx4 v[132:135], %[offO], %[whh] offset:16\n\t"
        "global_load_dwordx4 v[136:139], %[offO], %[whh] offset:32\n\t"
        "global_load_dwordx4 v[140:143], %[offO], %[whh] offset:48\n\t"
        "global_load_dwordx4 v[144:147], %[offO], %[whh] offset:64\n\t"
        "global_load_dwordx4 v[148:151], %[offO], %[whh] offset:80\n\t"
        "global_load_dwordx4 v[152:155], %[offO], %[whh] offset:96\n\t"
        "global_load_dwordx4 v[156:159], %[offO], %[whh] offset:112\n\t"
        // W_lin quarter-slice -> persistent v[188:219]
        "global_load_dwordx4 v[188:191], %[offL], %[wlin] offset:0\n\t"
        "global_load_dwordx4 v[192:195], %[offL], %[wlin] offset:16\n\t"
        "global_load_dwordx4 v[196:199], %[offL], %[wlin] offset:32\n\t"
        "global_load_dwordx4 v[200:203], %[offL], %[wlin] offset:48\n\t"
        "global_load_dwordx4 v[204:207], %[offL], %[wlin] offset:64\n\t"
        "global_load_dwordx4 v[208:211], %[offL], %[wlin] offset:80\n\t"
        "global_load_dwordx4 v[212:215], %[offL], %[wlin] offset:96\n\t"
        "global_load_dwordx4 v[216:219], %[offL], %[wlin] offset:112\n\t"
        "s_waitcnt vmcnt(0)\n\t"
        // fold: W' = W + wih * W_lin
        ".set K_I, 0\n"
        ".rept 32\n"
        " v_fma_f32 v[32+K_I],  %[wihi], v[188+K_I], v[32+K_I]\n"
        " v_fma_f32 v[64+K_I],  %[wihf], v[188+K_I], v[64+K_I]\n"
        " v_fma_f32 v[96+K_I],  %[wihg], v[188+K_I], v[96+K_I]\n"
        " v_fma_f32 v[128+K_I], %[wiho], v[188+K_I], v[128+K_I]\n"
        " .set K_I, K_I+1\n"
        ".endr\n"
        "s_movk_i32 s24, 1\n\t"
        // ---------------- main loop: t = 1 .. 2047 ----------------
        "1:\n\t"
        // h quarter: 8x b128 broadcast reads
        "ds_read_b128 v[0:3],   v172\n\t"
        "ds_read_b128 v[4:7],   v172 offset:16\n\t"
        "ds_read_b128 v[8:11],  v172 offset:32\n\t"
        "ds_read_b128 v[12:15], v172 offset:48\n\t"
        "ds_read_b128 v[16:19], v172 offset:64\n\t"
        "ds_read_b128 v[20:23], v172 offset:80\n\t"
        "ds_read_b128 v[24:27], v172 offset:96\n\t"
        "ds_read_b128 v[28:31], v172 offset:112\n\t"
        // quads 0-1 as soon as their reads land (6 still outstanding)
        "s_waitcnt lgkmcnt(6)\n\t"
        "v_mul_f32 v160, v0, v32\n\t"
        "v_mul_f32 v161, v0, v64\n\t"
        "v_mul_f32 v162, v0, v96\n\t"
        "v_mul_f32 v163, v0, v128\n\t"
        ".set K_I, 1\n"
        ".rept 7\n"
        " v_fma_f32 v160, v[0+K_I], v[32+K_I],  v160\n"
        " v_fma_f32 v161, v[0+K_I], v[64+K_I],  v161\n"
        " v_fma_f32 v162, v[0+K_I], v[96+K_I],  v162\n"
        " v_fma_f32 v163, v[0+K_I], v[128+K_I], v163\n"
        " .set K_I, K_I+1\n"
        ".endr\n"
        "s_waitcnt lgkmcnt(4)\n\t"
        ".rept 8\n"
        " v_fma_f32 v160, v[0+K_I], v[32+K_I],  v160\n"
        " v_fma_f32 v161, v[0+K_I], v[64+K_I],  v161\n"
        " v_fma_f32 v162, v[0+K_I], v[96+K_I],  v162\n"
        " v_fma_f32 v163, v[0+K_I], v[128+K_I], v163\n"
        " .set K_I, K_I+1\n"
        ".endr\n"
        "s_waitcnt lgkmcnt(2)\n\t"
        ".rept 8\n"
        " v_fma_f32 v160, v[0+K_I], v[32+K_I],  v160\n"
        " v_fma_f32 v161, v[0+K_I], v[64+K_I],  v161\n"
        " v_fma_f32 v162, v[0+K_I], v[96+K_I],  v162\n"
        " v_fma_f32 v163, v[0+K_I], v[128+K_I], v163\n"
        " .set K_I, K_I+1\n"
        ".endr\n"
        "s_waitcnt lgkmcnt(0)\n\t"
        ".rept 8\n"
        " v_fma_f32 v160, v[0+K_I], v[32+K_I],  v160\n"
        " v_fma_f32 v161, v[0+K_I], v[64+K_I],  v161\n"
        " v_fma_f32 v162, v[0+K_I], v[96+K_I],  v162\n"
        " v_fma_f32 v163, v[0+K_I], v[128+K_I], v163\n"
        " .set K_I, K_I+1\n"
        ".endr\n"
        // ---- quarter-combine in-register: DPP quad_perm xor1 then xor2.
        // 4-reg interleave gives >=3 insts between VALU write & DPP read.
        "v_add_f32_dpp v160, v160, v160 quad_perm:[1,0,3,2] row_mask:0xf bank_mask:0xf\n\t"
        "v_add_f32_dpp v161, v161, v161 quad_perm:[1,0,3,2] row_mask:0xf bank_mask:0xf\n\t"
        "v_add_f32_dpp v162, v162, v162 quad_perm:[1,0,3,2] row_mask:0xf bank_mask:0xf\n\t"
        "v_add_f32_dpp v163, v163, v163 quad_perm:[1,0,3,2] row_mask:0xf bank_mask:0xf\n\t"
        "v_add_f32_dpp v160, v160, v160 quad_perm:[2,3,0,1] row_mask:0xf bank_mask:0xf\n\t"
        "v_add_f32_dpp v161, v161, v161 quad_perm:[2,3,0,1] row_mask:0xf bank_mask:0xf\n\t"
        "v_add_f32_dpp v162, v162, v162 quad_perm:[2,3,0,1] row_mask:0xf bank_mask:0xf\n\t"
        "v_add_f32_dpp v163, v163, v163 quad_perm:[2,3,0,1] row_mask:0xf bank_mask:0xf\n\t"
        // + biases
        "v_add_f32 v160, v160, v177\n\t"
        "v_add_f32 v161, v161, v178\n\t"
        "v_add_f32 v162, v162, v179\n\t"
        "v_add_f32 v163, v163, v180\n\t"
        // ---- activations, TRANS-hazard-safe (interleaved, >=3 slack) ----
        "v_mul_f32 v164, 0xbfb8aa3b, v160\n\t"   // -log2(e)*i
        "v_mul_f32 v165, 0xbfb8aa3b, v161\n\t"   // -log2(e)*f
        "v_mul_f32 v166, 0x4038aa3b, v162\n\t"   //  2log2(e)*g
        "v_mul_f32 v167, 0xbfb8aa3b, v163\n\t"   // -log2(e)*o
        "v_exp_f32 v164, v164\n\t"
        "v_exp_f32 v165, v165\n\t"
        "v_exp_f32 v166, v166\n\t"
        "v_exp_f32 v167, v167\n\t"
        "v_add_f32 v164, 1.0, v164\n\t"
        "v_add_f32 v165, 1.0, v165\n\t"
        "v_add_f32 v166, 1.0, v166\n\t"
        "v_add_f32 v167, 1.0, v167\n\t"
        "v_rcp_f32 v166, v166\n\t"               // g-denom first
        "v_rcp_f32 v160, v164\n\t"               // i = sigmoid
        "v_rcp_f32 v161, v165\n\t"               // f = sigmoid
        "v_rcp_f32 v163, v167\n\t"               // o = sigmoid
        "v_fma_f32 v162, -2.0, v166, 1.0\n\t"    // g = tanh
        "v_mul_f32 v170, v160, v162\n\t"         // i*g
        "v_fma_f32 v168, v161, v168, v170\n\t"   // c = f*c + i*g
        // tanh(c) with explicit wait states
        "v_mul_f32 v170, 0x4038aa3b, v168\n\t"
        "v_exp_f32 v170, v170\n\t"
        "s_nop 1\n\t"
        "v_add_f32 v170, 1.0, v170\n\t"
        "v_rcp_f32 v170, v170\n\t"
        "s_nop 1\n\t"
        "v_fma_f32 v169, -2.0, v170, 1.0\n\t"
        "v_mul_f32 v169, v163, v169\n\t"         // hn = o * tanh(c)
        // publish h (q==0 lanes: hbuf dbuf + history ring)
        "s_mov_b64 s[22:23], exec\n\t"
        "s_mov_b64 exec, s[26:27]\n\t"
        "ds_write_b32 v173, v169\n\t"
        "ds_write_b32 v174, v169\n\t"
        "s_mov_b64 exec, s[22:23]\n\t"
        // advance addresses
        "v_add_u32 v172, v172, v175\n\t"
        "v_sub_u32 v173, v173, v175\n\t"
        "v_sub_u32 v175, 0, v175\n\t"
        "v_add_u32 v174, 0x210, v174\n\t"        // hist += 528
        "s_waitcnt lgkmcnt(0)\n\t"
        "s_barrier\n\t"
        // ---- flush every 128 steps: out[128k + j] = hist[j].WL + blin ----
        "s_and_b32 s20, s24, 127\n\t"
        "s_cmp_lg_u32 s20, 127\n\t"
        "s_cbranch_scc1 3f\n\t"
        "v_add_u32 v174, 0xfffef800, v174\n\t"   // hist write base wrap -67584
        "ds_read_b128 v[0:3],   v184\n\t"
        "ds_read_b128 v[4:7],   v184 offset:16\n\t"
        "ds_read_b128 v[8:11],  v184 offset:32\n\t"
        "ds_read_b128 v[12:15], v184 offset:48\n\t"
        "ds_read_b128 v[16:19], v184 offset:64\n\t"
        "ds_read_b128 v[20:23], v184 offset:80\n\t"
        "ds_read_b128 v[24:27], v184 offset:96\n\t"
        "ds_read_b128 v[28:31], v184 offset:112\n\t"
        "v_mov_b32 v164, 0\n\t"
        "s_waitcnt lgkmcnt(0)\n\t"
        ".set K_I, 0\n"
        ".rept 32\n"
        " v_fma_f32 v164, v[0+K_I], v[188+K_I], v164\n"
        " .set K_I, K_I+1\n"
        ".endr\n"
        "s_nop 1\n\t"
        "v_add_f32_dpp v164, v164, v164 quad_perm:[1,0,3,2] row_mask:0xf bank_mask:0xf\n\t"
        "s_nop 1\n\t"
        "v_add_f32_dpp v164, v164, v164 quad_perm:[2,3,0,1] row_mask:0xf bank_mask:0xf\n\t"
        "v_add_f32 v164, v164, v185\n\t"         // + b_lin
        "v_add_u32 v170, v176, v171\n\t"         // out byte = base + j*1024
        "s_mov_b64 s[22:23], exec\n\t"
        "s_mov_b64 exec, s[26:27]\n\t"
        "global_store_dword v170, v164, %[outp]\n\t"
        "s_mov_b64 exec, s[22:23]\n\t"
        "v_add_u32 v176, 0x20000, v176\n\t"      // out base += 128*256*4
        "s_barrier\n\t"                           // protect hist vs next iter
        "3:\n\t"
        "s_add_i32 s24, s24, 1\n\t"
        "s_cmp_lt_i32 s24, 2048\n\t"
        "s_cbranch_scc1 1b\n\t"
        :
        : [offI]"v"(offI), [offF]"v"(offF), [offG]"v"(offG), [offO]"v"(offO),
          [offL]"v"(offL), [whh]"s"(W_hh), [wlin]"s"(W_lin), [outp]"s"(out),
          [wihi]"v"(wih_i), [wihf]"v"(wih_f), [wihg]"v"(wih_g), [wiho]"v"(wih_o),
          [bi]"v"(bi_), [bf]"v"(bf_), [bg]"v"(bg_), [bo]"v"(bo_),
          [blin]"v"(blin), [c0]"v"(c),
          [vR]"v"(vR0), [vW]"v"(vW0), [hW]"v"(hW0), [fR]"v"(fR0),
          [jO]"v"(jO0), [vO]"v"(vO0), [tid]"v"(tid)
        : "memory", "scc", "vcc", "s20","s21","s22","s23","s24","s25","s26","s27",
          "v0","v1","v2","v3","v4","v5","v6","v7","v8","v9",
          "v10","v11","v12","v13","v14","v15","v16","v17","v18","v19",
          "v20","v21","v22","v23","v24","v25","v26","v27","v28","v29",
          "v30","v31","v32","v33","v34","v35","v36","v37","v38","v39",
          "v40","v41","v42","v43","v44","v45","v46","v47","v48","v49",
          "v50","v51","v52","v53","v54","v55","v56","v57","v58","v59",
          "v60","v61","v62","v63","v64","v65","v66","v67","v68","v69",
          "v70","v71","v72","v73","v74","v75","v76","v77","v78","v79",
          "v80","v81","v82","v83","v84","v85","v86","v87","v88","v89",
          "v90","v91","v92","v93","v94","v95","v96","v97","v98","v99",
          "v100","v101","v102","v103","v104","v105","v106","v107","v108","v109",
          "v110","v111","v112","v113","v114","v115","v116","v117","v118","v119",
          "v120","v121","v122","v123","v124","v125","v126","v127","v128","v129",
          "v130","v131","v132","v133","v134","v135","v136","v137","v138","v139",
          "v140","v141","v142","v143","v144","v145","v146","v147","v148","v149",
          "v150","v151","v152","v153","v154","v155","v156","v157","v158","v159",
          "v160","v161","v162","v163","v164","v165","v166","v167","v168","v169",
          "v170","v171","v172","v173","v174","v175","v176","v177","v178","v179",
          "v180","v181","v182","v183","v184","v185","v186","v187","v188","v189",
          "v190","v191","v192","v193","v194","v195","v196","v197","v198","v199",
          "v200","v201","v202","v203","v204","v205","v206","v207","v208","v209",
          "v210","v211","v212","v213","v214","v215","v216","v217","v218","v219");
    // no C epilogue: flush k=15 covers out[1920..2047]
}

extern "C" void kernel_launch(void* const* d_in, const int* in_sizes, int n_in,
                              void* d_out, int out_size, void* d_ws, size_t ws_size,
                              hipStream_t stream) {
    // inputs: 0 input (unused), 1 label, 2 h0, 3 W_ih, 4 W_hh,
    //         5 b_ih, 6 b_hh, 7 W_lin, 8 b_lin
    const int*   label = (const int*)  d_in[1];
    const float* h0    = (const float*)d_in[2];
    const float* W_ih  = (const float*)d_in[3];
    const float* W_hh  = (const float*)d_in[4];
    const float* b_ih  = (const float*)d_in[5];
    const float* b_hh  = (const float*)d_in[6];
    const float* W_lin = (const float*)d_in[7];
    const float* b_lin = (const float*)d_in[8];
    float* out = (float*)d_out;

    lstm_seq_kernel<<<dim3(BATCH), dim3(512), 0, stream>>>(
        label, h0, W_ih, W_hh, b_ih, b_hh, W_lin, b_lin, out);
}

// Round 17
// 1222.541 us; speedup vs baseline: 1.3798x; 1.0641x over previous
//
#include <hip/hip_runtime.h>
#include <math.h>

// Problem constants: T=2048, B=256, H=128, IN_DIM=1, NUM_DATA=4096
#define T_STEPS 2048
#define BATCH   256
#define HDIM    128

__device__ __forceinline__ float fast_rcp(float x) { return __builtin_amdgcn_rcpf(x); }
__device__ __forceinline__ float sigmoid_f(float x) { return fast_rcp(1.0f + __expf(-x)); }
__device__ __forceinline__ float tanh_f(float x) {
    float e = __expf(2.0f * x);
    return 1.0f - 2.0f * fast_rcp(e + 1.0f);
}

#define REP8(M) M(0) M(1) M(2) M(3) M(4) M(5) M(6) M(7)

// R17 = R16 (packed-fp32 GEMV: 64 v_pk_fma_f32 replaces 128 v_fma_f32)
// with the R16 BUG fixed: R16 seeded EVERY lane's accumulator with the
// full bias, and the DPP quad-combine sums 4 lanes -> gates got 4x bias
// (absmax 6.9e-2). Fix: seed with bias*0.25 (exact pow2 scale, computed in
// C); the quad-combine reconstructs exactly one bias. Tree-rounding diffs
// are ~1ulp and the recurrence is contracting (R13-R15 absmax 0.0).
// Register map: h v[0:31], wi v[32:63], wf v[64:95], wg v[96:127],
// wo v[128:159], acc pairs v[160:167], c v168, hn v169, tmp v170,
// jO v171, rd v172, wr v173, histwr v174, toggle v175, outbase v176,
// flushrd v184, blin v185, WL v[188:219], bias/4 pairs v[220:227].
__global__ __launch_bounds__(512, 2)
void lstm_seq_kernel(const int*   __restrict__ label,
                     const float* __restrict__ h0,     // (1, 4096, 128)
                     const float* __restrict__ W_ih,   // (512, 1)
                     const float* __restrict__ W_hh,   // (512, 128)
                     const float* __restrict__ b_ih,   // (512,)
                     const float* __restrict__ b_hh,   // (512,)
                     const float* __restrict__ W_lin,  // (1, 128)
                     const float* __restrict__ b_lin,  // (1,)
                     float*       __restrict__ out)    // (T, B, 1)
{
    const int tid   = threadIdx.x;
    const int batch = blockIdx.x;
    const int m     = tid >> 2;     // h element 0..127 (also flush t-slot j)
    const int q     = tid & 3;      // K-quarter 0..3
    const int q8    = q * 8;

    const int ri = m, rf = m + 128, rg = m + 256, ro = m + 384;

    __shared__ float hbuf[2][160];                                  // dbuf h
    __shared__ __attribute__((aligned(16))) float hist[128 * 132];  // y ring

    const float4* W4 = (const float4*)W_hh;
    const float4* L4 = (const float4*)W_lin;

    // ---- C-side load + fold (used only for step 0) ----
    #define DECL_W(i) \
        float4 wi##i = W4[ri * 32 + q8 + (i)]; \
        float4 wf##i = W4[rf * 32 + q8 + (i)]; \
        float4 wg##i = W4[rg * 32 + q8 + (i)]; \
        float4 wo##i = W4[ro * 32 + q8 + (i)];
    REP8(DECL_W)

    const float wih_i = W_ih[ri], wih_f = W_ih[rf];
    const float wih_g = W_ih[rg], wih_o = W_ih[ro];
    const float blin  = b_lin[0];

    const float bi_ = b_ih[ri] + b_hh[ri] + wih_i * blin;
    const float bf_ = b_ih[rf] + b_hh[rf] + wih_f * blin;
    const float bg_ = b_ih[rg] + b_hh[rg] + wih_g * blin;
    const float bo_ = b_ih[ro] + b_hh[ro] + wih_o * blin;

    // R17 fix: quarter-seed biases (the DPP quad-combine sums 4 lanes,
    // so each lane seeds bias/4; *0.25f is exact).
    const float bi4_ = bi_ * 0.25f;
    const float bf4_ = bf_ * 0.25f;
    const float bg4_ = bg_ * 0.25f;
    const float bo4_ = bo_ * 0.25f;

    #define FOLD_W(i) { float4 lv = L4[q8 + (i)]; \
        wi##i.x = fmaf(wih_i, lv.x, wi##i.x); wi##i.y = fmaf(wih_i, lv.y, wi##i.y); \
        wi##i.z = fmaf(wih_i, lv.z, wi##i.z); wi##i.w = fmaf(wih_i, lv.w, wi##i.w); \
        wf##i.x = fmaf(wih_f, lv.x, wf##i.x); wf##i.y = fmaf(wih_f, lv.y, wf##i.y); \
        wf##i.z = fmaf(wih_f, lv.z, wf##i.z); wf##i.w = fmaf(wih_f, lv.w, wf##i.w); \
        wg##i.x = fmaf(wih_g, lv.x, wg##i.x); wg##i.y = fmaf(wih_g, lv.y, wg##i.y); \
        wg##i.z = fmaf(wih_g, lv.z, wg##i.z); wg##i.w = fmaf(wih_g, lv.w, wg##i.w); \
        wo##i.x = fmaf(wih_o, lv.x, wo##i.x); wo##i.y = fmaf(wih_o, lv.y, wo##i.y); \
        wo##i.z = fmaf(wih_o, lv.z, wo##i.z); wo##i.w = fmaf(wih_o, lv.w, wo##i.w); }
    REP8(FOLD_W)

    const int   lane = tid & 63;
    const int   ya0w = lane + ((lane >> 5) << 2);   // word of h[lane] in hbuf
    const float wl_a = W_lin[lane];
    const float wl_b = W_lin[lane + 64];
    const int   hword = m + ((m >> 5) << 2);        // hbuf write word for m

    // ---- init h into buf0 ----
    if (tid < HDIM) hbuf[0][tid + ((tid >> 5) << 2)] = h0[label[batch] * HDIM + tid];
    __syncthreads();

    // y_init (uniform across waves) for the t=0 bias correction
    float p0 = hbuf[0][ya0w] * wl_a + hbuf[0][ya0w + 72] * wl_b;
    #pragma unroll
    for (int off = 1; off < 64; off <<= 1) p0 += __shfl_xor(p0, off, 64);
    const float y0 = p0 + blin;

    const float cbi = bi_ - wih_i * y0;
    const float cbf = bf_ - wih_f * y0;
    const float cbg = bg_ - wih_g * y0;
    const float cbo = bo_ - wih_o * y0;

    // ---- step 0 in C: read buf0, write state s=1 into buf1 AND hist[0] ----
    const float4* hq0 = (const float4*)(&hbuf[0][0] + 36 * q);
    float ai = 0.f, af = 0.f, ag = 0.f, ao = 0.f;
    #define DOT4(i) { float4 hv = hq0[(i)]; \
        ai = fmaf(hv.x, wi##i.x, ai); ai = fmaf(hv.y, wi##i.y, ai); \
        ai = fmaf(hv.z, wi##i.z, ai); ai = fmaf(hv.w, wi##i.w, ai); \
        af = fmaf(hv.x, wf##i.x, af); af = fmaf(hv.y, wf##i.y, af); \
        af = fmaf(hv.z, wf##i.z, af); af = fmaf(hv.w, wf##i.w, af); \
        ag = fmaf(hv.x, wg##i.x, ag); ag = fmaf(hv.y, wg##i.y, ag); \
        ag = fmaf(hv.z, wg##i.z, ag); ag = fmaf(hv.w, wg##i.w, ag); \
        ao = fmaf(hv.x, wo##i.x, ao); ao = fmaf(hv.y, wo##i.y, ao); \
        ao = fmaf(hv.z, wo##i.z, ao); ao = fmaf(hv.w, wo##i.w, ao); }
    REP8(DOT4)
    ai += __shfl_xor(ai, 1, 64); af += __shfl_xor(af, 1, 64);
    ag += __shfl_xor(ag, 1, 64); ao += __shfl_xor(ao, 1, 64);
    ai += __shfl_xor(ai, 2, 64); af += __shfl_xor(af, 2, 64);
    ag += __shfl_xor(ag, 2, 64); ao += __shfl_xor(ao, 2, 64);
    const float iv0 = sigmoid_f(ai + cbi);
    const float fv0 = sigmoid_f(af + cbf);
    const float gv0 = tanh_f  (ag + cbg);
    const float ov0 = sigmoid_f(ao + cbo);
    float c = iv0 * gv0;                 // c_prev = 0
    const float hn0 = ov0 * tanh_f(c);
    if (q == 0) { hbuf[1][hword] = hn0; hist[m] = hn0; }
    __syncthreads();

    // ---- asm operand prep ----
    const unsigned ldsA  = (unsigned)(unsigned long long)(&hbuf[0][0]);
    const unsigned histB = (unsigned)(unsigned long long)(&hist[0]);
    const unsigned vR0 = ldsA + 640u + 144u * (unsigned)q;   // read buf1
    const unsigned vW0 = ldsA + 4u * (unsigned)hword;        // write buf0
    const unsigned hW0 = histB + 528u + 4u * (unsigned)m;    // hist slot1,word m
    const unsigned fR0 = histB + 528u * (unsigned)m + 128u * (unsigned)q;
    const unsigned jO0 = 1024u * (unsigned)m;                // out offset j*1024
    const unsigned vO0 = 4u * (unsigned)batch;               // out[0] byte
    const unsigned offI = (unsigned)(ri * 512 + q * 128);
    const unsigned offF = (unsigned)(rf * 512 + q * 128);
    const unsigned offG = (unsigned)(rg * 512 + q * 128);
    const unsigned offO = (unsigned)(ro * 512 + q * 128);
    const unsigned offL = (unsigned)(q * 128);

    asm volatile(
        // ---------------- prologue: fixed-reg setup ----------------
        "v_mov_b32 v220, %[bi]\n\t"
        "v_mov_b32 v221, 0\n\t"
        "v_mov_b32 v222, %[bf]\n\t"
        "v_mov_b32 v223, 0\n\t"
        "v_mov_b32 v224, %[bg]\n\t"
        "v_mov_b32 v225, 0\n\t"
        "v_mov_b32 v226, %[bo]\n\t"
        "v_mov_b32 v227, 0\n\t"
        "v_mov_b32 v185, %[blin]\n\t"
        "v_mov_b32 v168, %[c0]\n\t"
        "v_mov_b32 v172, %[vR]\n\t"
        "v_mov_b32 v173, %[vW]\n\t"
        "v_mov_b32 v174, %[hW]\n\t"
        "v_mov_b32 v184, %[fR]\n\t"
        "v_mov_b32 v171, %[jO]\n\t"
        "v_mov_b32 v176, %[vO]\n\t"
        "v_mov_b32 v175, 0xfffffd80\n\t"      // hbuf toggle = -640
        // q==0 store mask -> s[26:27]
        "v_and_b32 v170, 3, %[tid]\n\t"
        "v_cmp_eq_u32 vcc, 0, v170\n\t"
        "s_nop 4\n\t"
        "s_mov_b64 s[26:27], vcc\n\t"
        // weights: 8x dwordx4 per gate into fixed quads
        "global_load_dwordx4 v[32:35], %[offI], %[whh] offset:0\n\t"
        "global_load_dwordx4 v[36:39], %[offI], %[whh] offset:16\n\t"
        "global_load_dwordx4 v[40:43], %[offI], %[whh] offset:32\n\t"
        "global_load_dwordx4 v[44:47], %[offI], %[whh] offset:48\n\t"
        "global_load_dwordx4 v[48:51], %[offI], %[whh] offset:64\n\t"
        "global_load_dwordx4 v[52:55], %[offI], %[whh] offset:80\n\t"
        "global_load_dwordx4 v[56:59], %[offI], %[whh] offset:96\n\t"
        "global_load_dwordx4 v[60:63], %[offI], %[whh] offset:112\n\t"
        "global_load_dwordx4 v[64:67], %[offF], %[whh] offset:0\n\t"
        "global_load_dwordx4 v[68:71], %[offF], %[whh] offset:16\n\t"
        "global_load_dwordx4 v[72:75], %[offF], %[whh] offset:32\n\t"
        "global_load_dwordx4 v[76:79], %[offF], %[whh] offset:48\n\t"
        "global_load_dwordx4 v[80:83], %[offF], %[whh] offset:64\n\t"
        "global_load_dwordx4 v[84:87], %[offF], %[whh] offset:80\n\t"
        "global_load_dwordx4 v[88:91], %[offF], %[whh] offset:96\n\t"
        "global_load_dwordx4 v[92:95], %[offF], %[whh] offset:112\n\t"
        "global_load_dwordx4 v[96:99], %[offG], %[whh] offset:0\n\t"
        "global_load_dwordx4 v[100:103], %[offG], %[whh] offset:16\n\t"
        "global_load_dwordx4 v[104:107], %[offG], %[whh] offset:32\n\t"
        "global_load_dwordx4 v[108:111], %[offG], %[whh] offset:48\n\t"
        "global_load_dwordx4 v[112:115], %[offG], %[whh] offset:64\n\t"
        "global_load_dwordx4 v[116:119], %[offG], %[whh] offset:80\n\t"
        "global_load_dwordx4 v[120:123], %[offG], %[whh] offset:96\n\t"
        "global_load_dwordx4 v[124:127], %[offG], %[whh] offset:112\n\t"
        "global_load_dwordx4 v[128:131], %[offO], %[whh] offset:0\n\t"
        "global_load_dwordx4 v[132:135], %[offO], %[whh] offset:16\n\t"
        "global_load_dwordx4 v[136:139], %[offO], %[whh] offset:32\n\t"
        "global_load_dwordx4 v[140:143], %[offO], %[whh] offset:48\n\t"
        "global_load_dwordx4 v[144:147], %[offO], %[whh] offset:64\n\t"
        "global_load_dwordx4 v[148:151], %[offO], %[whh] offset:80\n\t"
        "global_load_dwordx4 v[152:155], %[offO], %[whh] offset:96\n\t"
        "global_load_dwordx4 v[156:159], %[offO], %[whh] offset:112\n\t"
        // W_lin quarter-slice -> persistent v[188:219]
        "global_load_dwordx4 v[188:191], %[offL], %[wlin] offset:0\n\t"
        "global_load_dwordx4 v[192:195], %[offL], %[wlin] offset:16\n\t"
        "global_load_dwordx4 v[196:199], %[offL], %[wlin] offset:32\n\t"
        "global_load_dwordx4 v[200:203], %[offL], %[wlin] offset:48\n\t"
        "global_load_dwordx4 v[204:207], %[offL], %[wlin] offset:64\n\t"
        "global_load_dwordx4 v[208:211], %[offL], %[wlin] offset:80\n\t"
        "global_load_dwordx4 v[212:215], %[offL], %[wlin] offset:96\n\t"
        "global_load_dwordx4 v[216:219], %[offL], %[wlin] offset:112\n\t"
        "s_waitcnt vmcnt(0)\n\t"
        // fold: W' = W + wih * W_lin
        ".set K_I, 0\n"
        ".rept 32\n"
        " v_fma_f32 v[32+K_I],  %[wihi], v[188+K_I], v[32+K_I]\n"
        " v_fma_f32 v[64+K_I],  %[wihf], v[188+K_I], v[64+K_I]\n"
        " v_fma_f32 v[96+K_I],  %[wihg], v[188+K_I], v[96+K_I]\n"
        " v_fma_f32 v[128+K_I], %[wiho], v[188+K_I], v[128+K_I]\n"
        " .set K_I, K_I+1\n"
        ".endr\n"
        "s_movk_i32 s24, 1\n\t"
        // ---------------- main loop: t = 1 .. 2047 ----------------
        "1:\n\t"
        // h quarter: 8x b128 broadcast reads
        "ds_read_b128 v[0:3],   v172\n\t"
        "ds_read_b128 v[4:7],   v172 offset:16\n\t"
        "ds_read_b128 v[8:11],  v172 offset:32\n\t"
        "ds_read_b128 v[12:15], v172 offset:48\n\t"
        "ds_read_b128 v[16:19], v172 offset:64\n\t"
        "ds_read_b128 v[20:23], v172 offset:80\n\t"
        "ds_read_b128 v[24:27], v172 offset:96\n\t"
        "ds_read_b128 v[28:31], v172 offset:112\n\t"
        // ---- packed GEMV: pairs 0-3 once reads 0-1 land ----
        "s_waitcnt lgkmcnt(6)\n\t"
        "v_pk_fma_f32 v[160:161], v[0:1], v[32:33], v[220:221]\n\t"
        "v_pk_fma_f32 v[162:163], v[0:1], v[64:65], v[222:223]\n\t"
        "v_pk_fma_f32 v[164:165], v[0:1], v[96:97], v[224:225]\n\t"
        "v_pk_fma_f32 v[166:167], v[0:1], v[128:129], v[226:227]\n\t"
        ".set K_I, 2\n"
        ".rept 3\n"
        " v_pk_fma_f32 v[160:161], v[K_I:K_I+1], v[32+K_I:33+K_I], v[160:161]\n"
        " v_pk_fma_f32 v[162:163], v[K_I:K_I+1], v[64+K_I:65+K_I], v[162:163]\n"
        " v_pk_fma_f32 v[164:165], v[K_I:K_I+1], v[96+K_I:97+K_I], v[164:165]\n"
        " v_pk_fma_f32 v[166:167], v[K_I:K_I+1], v[128+K_I:129+K_I], v[166:167]\n"
        " .set K_I, K_I+2\n"
        ".endr\n"
        "s_waitcnt lgkmcnt(4)\n\t"
        ".rept 4\n"
        " v_pk_fma_f32 v[160:161], v[K_I:K_I+1], v[32+K_I:33+K_I], v[160:161]\n"
        " v_pk_fma_f32 v[162:163], v[K_I:K_I+1], v[64+K_I:65+K_I], v[162:163]\n"
        " v_pk_fma_f32 v[164:165], v[K_I:K_I+1], v[96+K_I:97+K_I], v[164:165]\n"
        " v_pk_fma_f32 v[166:167], v[K_I:K_I+1], v[128+K_I:129+K_I], v[166:167]\n"
        " .set K_I, K_I+2\n"
        ".endr\n"
        "s_waitcnt lgkmcnt(2)\n\t"
        ".rept 4\n"
        " v_pk_fma_f32 v[160:161], v[K_I:K_I+1], v[32+K_I:33+K_I], v[160:161]\n"
        " v_pk_fma_f32 v[162:163], v[K_I:K_I+1], v[64+K_I:65+K_I], v[162:163]\n"
        " v_pk_fma_f32 v[164:165], v[K_I:K_I+1], v[96+K_I:97+K_I], v[164:165]\n"
        " v_pk_fma_f32 v[166:167], v[K_I:K_I+1], v[128+K_I:129+K_I], v[166:167]\n"
        " .set K_I, K_I+2\n"
        ".endr\n"
        "s_waitcnt lgkmcnt(0)\n\t"
        ".rept 4\n"
        " v_pk_fma_f32 v[160:161], v[K_I:K_I+1], v[32+K_I:33+K_I], v[160:161]\n"
        " v_pk_fma_f32 v[162:163], v[K_I:K_I+1], v[64+K_I:65+K_I], v[162:163]\n"
        " v_pk_fma_f32 v[164:165], v[K_I:K_I+1], v[96+K_I:97+K_I], v[164:165]\n"
        " v_pk_fma_f32 v[166:167], v[K_I:K_I+1], v[128+K_I:129+K_I], v[166:167]\n"
        " .set K_I, K_I+2\n"
        ".endr\n"
        // ---- collapse lo+hi (4 independent adds) ----
        "v_add_f32 v160, v160, v161\n\t"
        "v_add_f32 v162, v162, v163\n\t"
        "v_add_f32 v164, v164, v165\n\t"
        "v_add_f32 v166, v166, v167\n\t"
        // ---- quarter-combine in-register: DPP quad_perm xor1 then xor2 ----
        "v_add_f32_dpp v160, v160, v160 quad_perm:[1,0,3,2] row_mask:0xf bank_mask:0xf\n\t"
        "v_add_f32_dpp v162, v162, v162 quad_perm:[1,0,3,2] row_mask:0xf bank_mask:0xf\n\t"
        "v_add_f32_dpp v164, v164, v164 quad_perm:[1,0,3,2] row_mask:0xf bank_mask:0xf\n\t"
        "v_add_f32_dpp v166, v166, v166 quad_perm:[1,0,3,2] row_mask:0xf bank_mask:0xf\n\t"
        "v_add_f32_dpp v160, v160, v160 quad_perm:[2,3,0,1] row_mask:0xf bank_mask:0xf\n\t"
        "v_add_f32_dpp v162, v162, v162 quad_perm:[2,3,0,1] row_mask:0xf bank_mask:0xf\n\t"
        "v_add_f32_dpp v164, v164, v164 quad_perm:[2,3,0,1] row_mask:0xf bank_mask:0xf\n\t"
        "v_add_f32_dpp v166, v166, v166 quad_perm:[2,3,0,1] row_mask:0xf bank_mask:0xf\n\t"
        // ---- activations (i=v160, f=v162, g=v164, o=v166), trans-safe ----
        "v_mul_f32 v161, 0xbfb8aa3b, v160\n\t"   // -log2(e)*i
        "v_mul_f32 v163, 0xbfb8aa3b, v162\n\t"   // -log2(e)*f
        "v_mul_f32 v165, 0x4038aa3b, v164\n\t"   //  2log2(e)*g
        "v_mul_f32 v167, 0xbfb8aa3b, v166\n\t"   // -log2(e)*o
        "v_exp_f32 v161, v161\n\t"
        "v_exp_f32 v163, v163\n\t"
        "v_exp_f32 v165, v165\n\t"
        "v_exp_f32 v167, v167\n\t"
        "v_add_f32 v161, 1.0, v161\n\t"
        "v_add_f32 v163, 1.0, v163\n\t"
        "v_add_f32 v165, 1.0, v165\n\t"
        "v_add_f32 v167, 1.0, v167\n\t"
        "v_rcp_f32 v165, v165\n\t"               // g-denom first
        "v_rcp_f32 v160, v161\n\t"               // i = sigmoid
        "v_rcp_f32 v162, v163\n\t"               // f = sigmoid
        "v_rcp_f32 v166, v167\n\t"               // o = sigmoid
        "v_fma_f32 v164, -2.0, v165, 1.0\n\t"    // g = tanh
        "v_mul_f32 v170, v160, v164\n\t"         // i*g
        "v_fma_f32 v168, v162, v168, v170\n\t"   // c = f*c + i*g
        // tanh(c) with explicit wait states
        "v_mul_f32 v170, 0x4038aa3b, v168\n\t"
        "v_exp_f32 v170, v170\n\t"
        "s_nop 1\n\t"
        "v_add_f32 v170, 1.0, v170\n\t"
        "v_rcp_f32 v170, v170\n\t"
        "s_nop 1\n\t"
        "v_fma_f32 v169, -2.0, v170, 1.0\n\t"
        "v_mul_f32 v169, v166, v169\n\t"         // hn = o * tanh(c)
        // publish h (q==0 lanes: hbuf dbuf + history ring)
        "s_mov_b64 s[22:23], exec\n\t"
        "s_mov_b64 exec, s[26:27]\n\t"
        "ds_write_b32 v173, v169\n\t"
        "ds_write_b32 v174, v169\n\t"
        "s_mov_b64 exec, s[22:23]\n\t"
        // advance addresses
        "v_add_u32 v172, v172, v175\n\t"
        "v_sub_u32 v173, v173, v175\n\t"
        "v_sub_u32 v175, 0, v175\n\t"
        "v_add_u32 v174, 0x210, v174\n\t"        // hist += 528
        "s_waitcnt lgkmcnt(0)\n\t"
        "s_barrier\n\t"
        // ---- flush every 128 steps: out[128k + j] = hist[j].WL + blin ----
        "s_and_b32 s20, s24, 127\n\t"
        "s_cmp_lg_u32 s20, 127\n\t"
        "s_cbranch_scc1 3f\n\t"
        "v_add_u32 v174, 0xfffef800, v174\n\t"   // hist write base wrap -67584
        "ds_read_b128 v[0:3],   v184\n\t"
        "ds_read_b128 v[4:7],   v184 offset:16\n\t"
        "ds_read_b128 v[8:11],  v184 offset:32\n\t"
        "ds_read_b128 v[12:15], v184 offset:48\n\t"
        "ds_read_b128 v[16:19], v184 offset:64\n\t"
        "ds_read_b128 v[20:23], v184 offset:80\n\t"
        "ds_read_b128 v[24:27], v184 offset:96\n\t"
        "ds_read_b128 v[28:31], v184 offset:112\n\t"
        "v_mov_b32 v164, 0\n\t"
        "s_waitcnt lgkmcnt(0)\n\t"
        ".set K_I, 0\n"
        ".rept 32\n"
        " v_fma_f32 v164, v[0+K_I], v[188+K_I], v164\n"
        " .set K_I, K_I+1\n"
        ".endr\n"
        "s_nop 1\n\t"
        "v_add_f32_dpp v164, v164, v164 quad_perm:[1,0,3,2] row_mask:0xf bank_mask:0xf\n\t"
        "s_nop 1\n\t"
        "v_add_f32_dpp v164, v164, v164 quad_perm:[2,3,0,1] row_mask:0xf bank_mask:0xf\n\t"
        "v_add_f32 v164, v164, v185\n\t"         // + b_lin
        "v_add_u32 v170, v176, v171\n\t"         // out byte = base + j*1024
        "s_mov_b64 s[22:23], exec\n\t"
        "s_mov_b64 exec, s[26:27]\n\t"
        "global_store_dword v170, v164, %[outp]\n\t"
        "s_mov_b64 exec, s[22:23]\n\t"
        "v_add_u32 v176, 0x20000, v176\n\t"      // out base += 128*256*4
        "s_barrier\n\t"                           // protect hist vs next iter
        "3:\n\t"
        "s_add_i32 s24, s24, 1\n\t"
        "s_cmp_lt_i32 s24, 2048\n\t"
        "s_cbranch_scc1 1b\n\t"
        :
        : [offI]"v"(offI), [offF]"v"(offF), [offG]"v"(offG), [offO]"v"(offO),
          [offL]"v"(offL), [whh]"s"(W_hh), [wlin]"s"(W_lin), [outp]"s"(out),
          [wihi]"v"(wih_i), [wihf]"v"(wih_f), [wihg]"v"(wih_g), [wiho]"v"(wih_o),
          [bi]"v"(bi4_), [bf]"v"(bf4_), [bg]"v"(bg4_), [bo]"v"(bo4_),
          [blin]"v"(blin), [c0]"v"(c),
          [vR]"v"(vR0), [vW]"v"(vW0), [hW]"v"(hW0), [fR]"v"(fR0),
          [jO]"v"(jO0), [vO]"v"(vO0), [tid]"v"(tid)
        : "memory", "scc", "vcc", "s20","s21","s22","s23","s24","s25","s26","s27",
          "v0","v1","v2","v3","v4","v5","v6","v7","v8","v9",
          "v10","v11","v12","v13","v14","v15","v16","v17","v18","v19",
          "v20","v21","v22","v23","v24","v25","v26","v27","v28","v29",
          "v30","v31","v32","v33","v34","v35","v36","v37","v38","v39",
          "v40","v41","v42","v43","v44","v45","v46","v47","v48","v49",
          "v50","v51","v52","v53","v54","v55","v56","v57","v58","v59",
          "v60","v61","v62","v63","v64","v65","v66","v67","v68","v69",
          "v70","v71","v72","v73","v74","v75","v76","v77","v78","v79",
          "v80","v81","v82","v83","v84","v85","v86","v87","v88","v89",
          "v90","v91","v92","v93","v94","v95","v96","v97","v98","v99",
          "v100","v101","v102","v103","v104","v105","v106","v107","v108","v109",
          "v110","v111","v112","v113","v114","v115","v116","v117","v118","v119",
          "v120","v121","v122","v123","v124","v125","v126","v127","v128","v129",
          "v130","v131","v132","v133","v134","v135","v136","v137","v138","v139",
          "v140","v141","v142","v143","v144","v145","v146","v147","v148","v149",
          "v150","v151","v152","v153","v154","v155","v156","v157","v158","v159",
          "v160","v161","v162","v163","v164","v165","v166","v167","v168","v169",
          "v170","v171","v172","v173","v174","v175","v176","v177","v178","v179",
          "v180","v181","v182","v183","v184","v185","v186","v187","v188","v189",
          "v190","v191","v192","v193","v194","v195","v196","v197","v198","v199",
          "v200","v201","v202","v203","v204","v205","v206","v207","v208","v209",
          "v210","v211","v212","v213","v214","v215","v216","v217","v218","v219",
          "v220","v221","v222","v223","v224","v225","v226","v227");
    // no C epilogue: flush k=15 covers out[1920..2047]
}

extern "C" void kernel_launch(void* const* d_in, const int* in_sizes, int n_in,
                              void* d_out, int out_size, void* d_ws, size_t ws_size,
                              hipStream_t stream) {
    // inputs: 0 input (unused), 1 label, 2 h0, 3 W_ih, 4 W_hh,
    //         5 b_ih, 6 b_hh, 7 W_lin, 8 b_lin
    const int*   label = (const int*)  d_in[1];
    const float* h0    = (const float*)d_in[2];
    const float* W_ih  = (const float*)d_in[3];
    const float* W_hh  = (const float*)d_in[4];
    const float* b_ih  = (const float*)d_in[5];
    const float* b_hh  = (const float*)d_in[6];
    const float* W_lin = (const float*)d_in[7];
    const float* b_lin = (const float*)d_in[8];
    float* out = (float*)d_out;

    lstm_seq_kernel<<<dim3(BATCH), dim3(512), 0, stream>>>(
        label, h0, W_ih, W_hh, b_ih, b_hh, W_lin, b_lin, out);
}

// Round 19
// 1191.409 us; speedup vs baseline: 1.4158x; 1.0261x over previous
//
#include <hip/hip_runtime.h>
#include <math.h>

// Problem constants: T=2048, B=256, H=128, IN_DIM=1, NUM_DATA=4096
#define T_STEPS 2048
#define BATCH   256
#define HDIM    128

__device__ __forceinline__ float fast_rcp(float x) { return __builtin_amdgcn_rcpf(x); }
__device__ __forceinline__ float sigmoid_f(float x) { return fast_rcp(1.0f + __expf(-x)); }
__device__ __forceinline__ float tanh_f(float x) {
    float e = __expf(2.0f * x);
    return 1.0f - 2.0f * fast_rcp(e + 1.0f);
}

#define REP8(M) M(0) M(1) M(2) M(3) M(4) M(5) M(6) M(7)

// R19 = R18 with the VOP3P alignment fix: v_pk_mul_f32 source pairs must be
// EVEN-aligned (assembler: "vgpr tuples must be 64 bit aligned"). Scale
// constants move from v[177:178]/v[179:180] (odd base) to v[178:179] /
// v[182:183] (even base). Nothing else changed vs R18:
//  * single 128-slot ring (576B slots) is both h storage and y history;
//    one ds_write/step, 2 addr adds, pre-wrap read-addr derivation.
//  * pk_fma GEMV (64 inst), DPP quad-combine, staggered lgkmcnt,
//    packed activation pre-scales, trans-hazard-safe spacing throughout.
// Register map: h v[0:31], wi v[32:63], wf v[64:95], wg v[96:127],
// wo v[128:159], acc pairs v[160:167], c v168, hn v169, tmp v170,
// jO v171, rdaddr v172, wraddr v174, outbase v176, scales v[178:179] &
// v[182:183], flushrd v184, blin v185, vD v186, WL v[188:219],
// bias/4 pairs v[220:227].
__global__ __launch_bounds__(512, 2)
void lstm_seq_kernel(const int*   __restrict__ label,
                     const float* __restrict__ h0,     // (1, 4096, 128)
                     const float* __restrict__ W_ih,   // (512, 1)
                     const float* __restrict__ W_hh,   // (512, 128)
                     const float* __restrict__ b_ih,   // (512,)
                     const float* __restrict__ b_hh,   // (512,)
                     const float* __restrict__ W_lin,  // (1, 128)
                     const float* __restrict__ b_lin,  // (1,)
                     float*       __restrict__ out)    // (T, B, 1)
{
    const int tid   = threadIdx.x;
    const int batch = blockIdx.x;
    const int m     = tid >> 2;     // h element 0..127 (also flush t-slot j)
    const int q     = tid & 3;      // K-quarter 0..3
    const int q8    = q * 8;

    const int ri = m, rf = m + 128, rg = m + 256, ro = m + 384;

    // 128 slots x 144 words = 73728 B. Slot k holds h_state_{k+1} (after
    // step k). Slot 127 doubles as h_init scratch for the C prologue.
    __shared__ __attribute__((aligned(16))) float hist[128 * 144];

    const float4* W4 = (const float4*)W_hh;
    const float4* L4 = (const float4*)W_lin;

    // ---- C-side load + fold (used only for step 0) ----
    #define DECL_W(i) \
        float4 wi##i = W4[ri * 32 + q8 + (i)]; \
        float4 wf##i = W4[rf * 32 + q8 + (i)]; \
        float4 wg##i = W4[rg * 32 + q8 + (i)]; \
        float4 wo##i = W4[ro * 32 + q8 + (i)];
    REP8(DECL_W)

    const float wih_i = W_ih[ri], wih_f = W_ih[rf];
    const float wih_g = W_ih[rg], wih_o = W_ih[ro];
    const float blin  = b_lin[0];

    const float bi_ = b_ih[ri] + b_hh[ri] + wih_i * blin;
    const float bf_ = b_ih[rf] + b_hh[rf] + wih_f * blin;
    const float bg_ = b_ih[rg] + b_hh[rg] + wih_g * blin;
    const float bo_ = b_ih[ro] + b_hh[ro] + wih_o * blin;

    // quarter-seed biases (DPP quad-combine sums 4 lanes -> bias/4 each)
    const float bi4_ = bi_ * 0.25f;
    const float bf4_ = bf_ * 0.25f;
    const float bg4_ = bg_ * 0.25f;
    const float bo4_ = bo_ * 0.25f;

    #define FOLD_W(i) { float4 lv = L4[q8 + (i)]; \
        wi##i.x = fmaf(wih_i, lv.x, wi##i.x); wi##i.y = fmaf(wih_i, lv.y, wi##i.y); \
        wi##i.z = fmaf(wih_i, lv.z, wi##i.z); wi##i.w = fmaf(wih_i, lv.w, wi##i.w); \
        wf##i.x = fmaf(wih_f, lv.x, wf##i.x); wf##i.y = fmaf(wih_f, lv.y, wf##i.y); \
        wf##i.z = fmaf(wih_f, lv.z, wf##i.z); wf##i.w = fmaf(wih_f, lv.w, wf##i.w); \
        wg##i.x = fmaf(wih_g, lv.x, wg##i.x); wg##i.y = fmaf(wih_g, lv.y, wg##i.y); \
        wg##i.z = fmaf(wih_g, lv.z, wg##i.z); wg##i.w = fmaf(wih_g, lv.w, wg##i.w); \
        wo##i.x = fmaf(wih_o, lv.x, wo##i.x); wo##i.y = fmaf(wih_o, lv.y, wo##i.y); \
        wo##i.z = fmaf(wih_o, lv.z, wo##i.z); wo##i.w = fmaf(wih_o, lv.w, wo##i.w); }
    REP8(FOLD_W)

    const int   lane = tid & 63;
    const int   ya0w = lane + ((lane >> 5) << 2);   // word of h[lane] in a slot
    const float wl_a = W_lin[lane];
    const float wl_b = W_lin[lane + 64];
    const int   hword = m + ((m >> 5) << 2);        // element word in a slot

    // ---- init h into slot 127 (scratch; overwritten at t=127) ----
    float* slotI = &hist[144 * 127];
    if (tid < HDIM) slotI[tid + ((tid >> 5) << 2)] = h0[label[batch] * HDIM + tid];
    __syncthreads();

    // y_init (uniform across waves) for the t=0 bias correction
    float p0 = slotI[ya0w] * wl_a + slotI[ya0w + 72] * wl_b;
    #pragma unroll
    for (int off = 1; off < 64; off <<= 1) p0 += __shfl_xor(p0, off, 64);
    const float y0 = p0 + blin;

    const float cbi = bi_ - wih_i * y0;
    const float cbf = bf_ - wih_f * y0;
    const float cbg = bg_ - wih_g * y0;
    const float cbo = bo_ - wih_o * y0;

    // ---- step 0 in C: read slot 127 (init), write state 1 into slot 0 ----
    const float4* hq0 = (const float4*)(slotI + 36 * q);
    float ai = 0.f, af = 0.f, ag = 0.f, ao = 0.f;
    #define DOT4(i) { float4 hv = hq0[(i)]; \
        ai = fmaf(hv.x, wi##i.x, ai); ai = fmaf(hv.y, wi##i.y, ai); \
        ai = fmaf(hv.z, wi##i.z, ai); ai = fmaf(hv.w, wi##i.w, ai); \
        af = fmaf(hv.x, wf##i.x, af); af = fmaf(hv.y, wf##i.y, af); \
        af = fmaf(hv.z, wf##i.z, af); af = fmaf(hv.w, wf##i.w, af); \
        ag = fmaf(hv.x, wg##i.x, ag); ag = fmaf(hv.y, wg##i.y, ag); \
        ag = fmaf(hv.z, wg##i.z, ag); ag = fmaf(hv.w, wg##i.w, ag); \
        ao = fmaf(hv.x, wo##i.x, ao); ao = fmaf(hv.y, wo##i.y, ao); \
        ao = fmaf(hv.z, wo##i.z, ao); ao = fmaf(hv.w, wo##i.w, ao); }
    REP8(DOT4)
    ai += __shfl_xor(ai, 1, 64); af += __shfl_xor(af, 1, 64);
    ag += __shfl_xor(ag, 1, 64); ao += __shfl_xor(ao, 1, 64);
    ai += __shfl_xor(ai, 2, 64); af += __shfl_xor(af, 2, 64);
    ag += __shfl_xor(ag, 2, 64); ao += __shfl_xor(ao, 2, 64);
    const float iv0 = sigmoid_f(ai + cbi);
    const float fv0 = sigmoid_f(af + cbf);
    const float gv0 = tanh_f  (ag + cbg);
    const float ov0 = sigmoid_f(ao + cbo);
    float c = iv0 * gv0;                 // c_prev = 0
    const float hn0 = ov0 * tanh_f(c);
    if (q == 0) hist[hword] = hn0;       // slot 0 = state 1
    __syncthreads();

    // ---- asm operand prep ----
    const unsigned histB = (unsigned)(unsigned long long)(&hist[0]);
    const unsigned vR0 = histB + 144u * (unsigned)q;           // slot0 quarter
    const unsigned hW0 = histB + 576u + 4u * (unsigned)hword;  // slot1 write
    const unsigned vD0 = (unsigned)(-576 + 144 * q - 4 * hword); // read-write
    const unsigned fR0 = histB + 576u * (unsigned)m + 144u * (unsigned)q;
    const unsigned jO0 = 1024u * (unsigned)m;                  // out j*1024
    const unsigned vO0 = 4u * (unsigned)batch;                 // out[0] byte
    const unsigned offI = (unsigned)(ri * 512 + q * 128);
    const unsigned offF = (unsigned)(rf * 512 + q * 128);
    const unsigned offG = (unsigned)(rg * 512 + q * 128);
    const unsigned offO = (unsigned)(ro * 512 + q * 128);
    const unsigned offL = (unsigned)(q * 128);

    asm volatile(
        // ---------------- prologue: fixed-reg setup ----------------
        "v_mov_b32 v220, %[bi]\n\t"
        "v_mov_b32 v221, 0\n\t"
        "v_mov_b32 v222, %[bf]\n\t"
        "v_mov_b32 v223, 0\n\t"
        "v_mov_b32 v224, %[bg]\n\t"
        "v_mov_b32 v225, 0\n\t"
        "v_mov_b32 v226, %[bo]\n\t"
        "v_mov_b32 v227, 0\n\t"
        "v_mov_b32 v178, 0xbfb8aa3b\n\t"      // -log2e (i pre-scale)
        "v_mov_b32 v179, 0xbfb8aa3b\n\t"      // -log2e (f pre-scale)
        "v_mov_b32 v182, 0x4038aa3b\n\t"      // 2log2e (g pre-scale)
        "v_mov_b32 v183, 0xbfb8aa3b\n\t"      // -log2e (o pre-scale)
        "v_mov_b32 v185, %[blin]\n\t"
        "v_mov_b32 v168, %[c0]\n\t"
        "v_mov_b32 v172, %[vR]\n\t"
        "v_mov_b32 v174, %[hW]\n\t"
        "v_mov_b32 v186, %[vD]\n\t"
        "v_mov_b32 v184, %[fR]\n\t"
        "v_mov_b32 v171, %[jO]\n\t"
        "v_mov_b32 v176, %[vO]\n\t"
        // q==0 store mask -> s[26:27]
        "v_and_b32 v170, 3, %[tid]\n\t"
        "v_cmp_eq_u32 vcc, 0, v170\n\t"
        "s_nop 4\n\t"
        "s_mov_b64 s[26:27], vcc\n\t"
        // weights: 8x dwordx4 per gate into fixed quads
        "global_load_dwordx4 v[32:35], %[offI], %[whh] offset:0\n\t"
        "global_load_dwordx4 v[36:39], %[offI], %[whh] offset:16\n\t"
        "global_load_dwordx4 v[40:43], %[offI], %[whh] offset:32\n\t"
        "global_load_dwordx4 v[44:47], %[offI], %[whh] offset:48\n\t"
        "global_load_dwordx4 v[48:51], %[offI], %[whh] offset:64\n\t"
        "global_load_dwordx4 v[52:55], %[offI], %[whh] offset:80\n\t"
        "global_load_dwordx4 v[56:59], %[offI], %[whh] offset:96\n\t"
        "global_load_dwordx4 v[60:63], %[offI], %[whh] offset:112\n\t"
        "global_load_dwordx4 v[64:67], %[offF], %[whh] offset:0\n\t"
        "global_load_dwordx4 v[68:71], %[offF], %[whh] offset:16\n\t"
        "global_load_dwordx4 v[72:75], %[offF], %[whh] offset:32\n\t"
        "global_load_dwordx4 v[76:79], %[offF], %[whh] offset:48\n\t"
        "global_load_dwordx4 v[80:83], %[offF], %[whh] offset:64\n\t"
        "global_load_dwordx4 v[84:87], %[offF], %[whh] offset:80\n\t"
        "global_load_dwordx4 v[88:91], %[offF], %[whh] offset:96\n\t"
        "global_load_dwordx4 v[92:95], %[offF], %[whh] offset:112\n\t"
        "global_load_dwordx4 v[96:99], %[offG], %[whh] offset:0\n\t"
        "global_load_dwordx4 v[100:103], %[offG], %[whh] offset:16\n\t"
        "global_load_dwordx4 v[104:107], %[offG], %[whh] offset:32\n\t"
        "global_load_dwordx4 v[108:111], %[offG], %[whh] offset:48\n\t"
        "global_load_dwordx4 v[112:115], %[offG], %[whh] offset:64\n\t"
        "global_load_dwordx4 v[116:119], %[offG], %[whh] offset:80\n\t"
        "global_load_dwordx4 v[120:123], %[offG], %[whh] offset:96\n\t"
        "global_load_dwordx4 v[124:127], %[offG], %[whh] offset:112\n\t"
        "global_load_dwordx4 v[128:131], %[offO], %[whh] offset:0\n\t"
        "global_load_dwordx4 v[132:135], %[offO], %[whh] offset:16\n\t"
        "global_load_dwordx4 v[136:139], %[offO], %[whh] offset:32\n\t"
        "global_load_dwordx4 v[140:143], %[offO], %[whh] offset:48\n\t"
        "global_load_dwordx4 v[144:147], %[offO], %[whh] offset:64\n\t"
        "global_load_dwordx4 v[148:151], %[offO], %[whh] offset:80\n\t"
        "global_load_dwordx4 v[152:155], %[offO], %[whh] offset:96\n\t"
        "global_load_dwordx4 v[156:159], %[offO], %[whh] offset:112\n\t"
        // W_lin quarter-slice -> persistent v[188:219]
        "global_load_dwordx4 v[188:191], %[offL], %[wlin] offset:0\n\t"
        "global_load_dwordx4 v[192:195], %[offL], %[wlin] offset:16\n\t"
        "global_load_dwordx4 v[196:199], %[offL], %[wlin] offset:32\n\t"
        "global_load_dwordx4 v[200:203], %[offL], %[wlin] offset:48\n\t"
        "global_load_dwordx4 v[204:207], %[offL], %[wlin] offset:64\n\t"
        "global_load_dwordx4 v[208:211], %[offL], %[wlin] offset:80\n\t"
        "global_load_dwordx4 v[212:215], %[offL], %[wlin] offset:96\n\t"
        "global_load_dwordx4 v[216:219], %[offL], %[wlin] offset:112\n\t"
        "s_waitcnt vmcnt(0)\n\t"
        // fold: W' = W + wih * W_lin
        ".set K_I, 0\n"
        ".rept 32\n"
        " v_fma_f32 v[32+K_I],  %[wihi], v[188+K_I], v[32+K_I]\n"
        " v_fma_f32 v[64+K_I],  %[wihf], v[188+K_I], v[64+K_I]\n"
        " v_fma_f32 v[96+K_I],  %[wihg], v[188+K_I], v[96+K_I]\n"
        " v_fma_f32 v[128+K_I], %[wiho], v[188+K_I], v[128+K_I]\n"
        " .set K_I, K_I+1\n"
        ".endr\n"
        "s_movk_i32 s24, 1\n\t"
        // ---------------- main loop: t = 1 .. 2047 ----------------
        "1:\n\t"
        // h quarter: 8x b128 broadcast reads from slot t-1
        "ds_read_b128 v[0:3],   v172\n\t"
        "ds_read_b128 v[4:7],   v172 offset:16\n\t"
        "ds_read_b128 v[8:11],  v172 offset:32\n\t"
        "ds_read_b128 v[12:15], v172 offset:48\n\t"
        "ds_read_b128 v[16:19], v172 offset:64\n\t"
        "ds_read_b128 v[20:23], v172 offset:80\n\t"
        "ds_read_b128 v[24:27], v172 offset:96\n\t"
        "ds_read_b128 v[28:31], v172 offset:112\n\t"
        // ---- packed GEMV: pairs 0-3 once reads 0-1 land ----
        "s_waitcnt lgkmcnt(6)\n\t"
        "v_pk_fma_f32 v[160:161], v[0:1], v[32:33], v[220:221]\n\t"
        "v_pk_fma_f32 v[162:163], v[0:1], v[64:65], v[222:223]\n\t"
        "v_pk_fma_f32 v[164:165], v[0:1], v[96:97], v[224:225]\n\t"
        "v_pk_fma_f32 v[166:167], v[0:1], v[128:129], v[226:227]\n\t"
        ".set K_I, 2\n"
        ".rept 3\n"
        " v_pk_fma_f32 v[160:161], v[K_I:K_I+1], v[32+K_I:33+K_I], v[160:161]\n"
        " v_pk_fma_f32 v[162:163], v[K_I:K_I+1], v[64+K_I:65+K_I], v[162:163]\n"
        " v_pk_fma_f32 v[164:165], v[K_I:K_I+1], v[96+K_I:97+K_I], v[164:165]\n"
        " v_pk_fma_f32 v[166:167], v[K_I:K_I+1], v[128+K_I:129+K_I], v[166:167]\n"
        " .set K_I, K_I+2\n"
        ".endr\n"
        "s_waitcnt lgkmcnt(4)\n\t"
        ".rept 4\n"
        " v_pk_fma_f32 v[160:161], v[K_I:K_I+1], v[32+K_I:33+K_I], v[160:161]\n"
        " v_pk_fma_f32 v[162:163], v[K_I:K_I+1], v[64+K_I:65+K_I], v[162:163]\n"
        " v_pk_fma_f32 v[164:165], v[K_I:K_I+1], v[96+K_I:97+K_I], v[164:165]\n"
        " v_pk_fma_f32 v[166:167], v[K_I:K_I+1], v[128+K_I:129+K_I], v[166:167]\n"
        " .set K_I, K_I+2\n"
        ".endr\n"
        "s_waitcnt lgkmcnt(2)\n\t"
        ".rept 4\n"
        " v_pk_fma_f32 v[160:161], v[K_I:K_I+1], v[32+K_I:33+K_I], v[160:161]\n"
        " v_pk_fma_f32 v[162:163], v[K_I:K_I+1], v[64+K_I:65+K_I], v[162:163]\n"
        " v_pk_fma_f32 v[164:165], v[K_I:K_I+1], v[96+K_I:97+K_I], v[164:165]\n"
        " v_pk_fma_f32 v[166:167], v[K_I:K_I+1], v[128+K_I:129+K_I], v[166:167]\n"
        " .set K_I, K_I+2\n"
        ".endr\n"
        "s_waitcnt lgkmcnt(0)\n\t"
        ".rept 4\n"
        " v_pk_fma_f32 v[160:161], v[K_I:K_I+1], v[32+K_I:33+K_I], v[160:161]\n"
        " v_pk_fma_f32 v[162:163], v[K_I:K_I+1], v[64+K_I:65+K_I], v[162:163]\n"
        " v_pk_fma_f32 v[164:165], v[K_I:K_I+1], v[96+K_I:97+K_I], v[164:165]\n"
        " v_pk_fma_f32 v[166:167], v[K_I:K_I+1], v[128+K_I:129+K_I], v[166:167]\n"
        " .set K_I, K_I+2\n"
        ".endr\n"
        // ---- collapse lo+hi into adjacent pairs: (i,f)->160,161 (g,o)->164,165
        "v_add_f32 v160, v160, v161\n\t"
        "v_add_f32 v161, v162, v163\n\t"
        "v_add_f32 v164, v164, v165\n\t"
        "v_add_f32 v165, v166, v167\n\t"
        // ---- quarter-combine in-register: DPP quad_perm xor1 then xor2 ----
        "v_add_f32_dpp v160, v160, v160 quad_perm:[1,0,3,2] row_mask:0xf bank_mask:0xf\n\t"
        "v_add_f32_dpp v161, v161, v161 quad_perm:[1,0,3,2] row_mask:0xf bank_mask:0xf\n\t"
        "v_add_f32_dpp v164, v164, v164 quad_perm:[1,0,3,2] row_mask:0xf bank_mask:0xf\n\t"
        "v_add_f32_dpp v165, v165, v165 quad_perm:[1,0,3,2] row_mask:0xf bank_mask:0xf\n\t"
        "v_add_f32_dpp v160, v160, v160 quad_perm:[2,3,0,1] row_mask:0xf bank_mask:0xf\n\t"
        "v_add_f32_dpp v161, v161, v161 quad_perm:[2,3,0,1] row_mask:0xf bank_mask:0xf\n\t"
        "v_add_f32_dpp v164, v164, v164 quad_perm:[2,3,0,1] row_mask:0xf bank_mask:0xf\n\t"
        "v_add_f32_dpp v165, v165, v165 quad_perm:[2,3,0,1] row_mask:0xf bank_mask:0xf\n\t"
        // ---- activations: packed pre-scale (even-aligned const pairs) ----
        "v_pk_mul_f32 v[162:163], v[178:179], v[160:161]\n\t"  // (-l2e*i, -l2e*f)
        "v_pk_mul_f32 v[166:167], v[182:183], v[164:165]\n\t"  // (2l2e*g, -l2e*o)
        "v_exp_f32 v162, v162\n\t"
        "v_exp_f32 v163, v163\n\t"
        "v_exp_f32 v166, v166\n\t"
        "v_exp_f32 v167, v167\n\t"
        "v_add_f32 v166, 1.0, v166\n\t"
        "v_add_f32 v167, 1.0, v167\n\t"
        "v_add_f32 v162, 1.0, v162\n\t"
        "v_add_f32 v163, 1.0, v163\n\t"
        "v_rcp_f32 v166, v166\n\t"               // g-denom first
        "v_rcp_f32 v162, v162\n\t"               // i = sigmoid
        "v_rcp_f32 v163, v163\n\t"               // f = sigmoid
        "v_rcp_f32 v167, v167\n\t"               // o = sigmoid
        "v_fma_f32 v164, -2.0, v166, 1.0\n\t"    // g = tanh
        "v_mul_f32 v170, v162, v164\n\t"         // i*g
        "v_fma_f32 v168, v163, v168, v170\n\t"   // c = f*c + i*g
        // tanh(c) with explicit wait states
        "v_mul_f32 v170, 0x4038aa3b, v168\n\t"
        "v_exp_f32 v170, v170\n\t"
        "s_nop 1\n\t"
        "v_add_f32 v170, 1.0, v170\n\t"
        "v_rcp_f32 v170, v170\n\t"
        "s_nop 1\n\t"
        "v_fma_f32 v169, -2.0, v170, 1.0\n\t"
        "v_mul_f32 v169, v167, v169\n\t"         // hn = o * tanh(c)
        // publish h into ring slot t (q==0 lanes)
        "s_mov_b64 s[22:23], exec\n\t"
        "s_mov_b64 exec, s[26:27]\n\t"
        "ds_write_b32 v174, v169\n\t"
        "s_mov_b64 exec, s[22:23]\n\t"
        // advance: write += 576; next read = write + vD (pre-wrap value!)
        "v_add_u32 v174, 0x240, v174\n\t"
        "v_add_u32 v172, v174, v186\n\t"
        "s_waitcnt lgkmcnt(0)\n\t"
        "s_barrier\n\t"
        // ---- flush every 128 steps: out[...] = hist[j].WL + blin ----
        "s_and_b32 s20, s24, 127\n\t"
        "s_cmp_lg_u32 s20, 127\n\t"
        "s_cbranch_scc1 3f\n\t"
        "v_add_u32 v174, 0xfffee000, v174\n\t"   // write base wrap: -73728
        "ds_read_b128 v[0:3],   v184\n\t"
        "ds_read_b128 v[4:7],   v184 offset:16\n\t"
        "ds_read_b128 v[8:11],  v184 offset:32\n\t"
        "ds_read_b128 v[12:15], v184 offset:48\n\t"
        "ds_read_b128 v[16:19], v184 offset:64\n\t"
        "ds_read_b128 v[20:23], v184 offset:80\n\t"
        "ds_read_b128 v[24:27], v184 offset:96\n\t"
        "ds_read_b128 v[28:31], v184 offset:112\n\t"
        "v_mov_b32 v164, 0\n\t"
        "s_waitcnt lgkmcnt(0)\n\t"
        ".set K_I, 0\n"
        ".rept 32\n"
        " v_fma_f32 v164, v[0+K_I], v[188+K_I], v164\n"
        " .set K_I, K_I+1\n"
        ".endr\n"
        "s_nop 1\n\t"
        "v_add_f32_dpp v164, v164, v164 quad_perm:[1,0,3,2] row_mask:0xf bank_mask:0xf\n\t"
        "s_nop 1\n\t"
        "v_add_f32_dpp v164, v164, v164 quad_perm:[2,3,0,1] row_mask:0xf bank_mask:0xf\n\t"
        "v_add_f32 v164, v164, v185\n\t"         // + b_lin
        "v_add_u32 v170, v176, v171\n\t"         // out byte = base + j*1024
        "s_mov_b64 s[22:23], exec\n\t"
        "s_mov_b64 exec, s[26:27]\n\t"
        "global_store_dword v170, v164, %[outp]\n\t"
        "s_mov_b64 exec, s[22:23]\n\t"
        "v_add_u32 v176, 0x20000, v176\n\t"      // out base += 128*256*4
        "s_barrier\n\t"                           // protect hist vs next iter
        "3:\n\t"
        "s_add_i32 s24, s24, 1\n\t"
        "s_cmp_lt_i32 s24, 2048\n\t"
        "s_cbranch_scc1 1b\n\t"
        :
        : [offI]"v"(offI), [offF]"v"(offF), [offG]"v"(offG), [offO]"v"(offO),
          [offL]"v"(offL), [whh]"s"(W_hh), [wlin]"s"(W_lin), [outp]"s"(out),
          [wihi]"v"(wih_i), [wihf]"v"(wih_f), [wihg]"v"(wih_g), [wiho]"v"(wih_o),
          [bi]"v"(bi4_), [bf]"v"(bf4_), [bg]"v"(bg4_), [bo]"v"(bo4_),
          [blin]"v"(blin), [c0]"v"(c),
          [vR]"v"(vR0), [hW]"v"(hW0), [vD]"v"(vD0), [fR]"v"(fR0),
          [jO]"v"(jO0), [vO]"v"(vO0), [tid]"v"(tid)
        : "memory", "scc", "vcc", "s20","s21","s22","s23","s24","s25","s26","s27",
          "v0","v1","v2","v3","v4","v5","v6","v7","v8","v9",
          "v10","v11","v12","v13","v14","v15","v16","v17","v18","v19",
          "v20","v21","v22","v23","v24","v25","v26","v27","v28","v29",
          "v30","v31","v32","v33","v34","v35","v36","v37","v38","v39",
          "v40","v41","v42","v43","v44","v45","v46","v47","v48","v49",
          "v50","v51","v52","v53","v54","v55","v56","v57","v58","v59",
          "v60","v61","v62","v63","v64","v65","v66","v67","v68","v69",
          "v70","v71","v72","v73","v74","v75","v76","v77","v78","v79",
          "v80","v81","v82","v83","v84","v85","v86","v87","v88","v89",
          "v90","v91","v92","v93","v94","v95","v96","v97","v98","v99",
          "v100","v101","v102","v103","v104","v105","v106","v107","v108","v109",
          "v110","v111","v112","v113","v114","v115","v116","v117","v118","v119",
          "v120","v121","v122","v123","v124","v125","v126","v127","v128","v129",
          "v130","v131","v132","v133","v134","v135","v136","v137","v138","v139",
          "v140","v141","v142","v143","v144","v145","v146","v147","v148","v149",
          "v150","v151","v152","v153","v154","v155","v156","v157","v158","v159",
          "v160","v161","v162","v163","v164","v165","v166","v167","v168","v169",
          "v170","v171","v172","v173","v174","v175","v176","v177","v178","v179",
          "v180","v181","v182","v183","v184","v185","v186","v187","v188","v189",
          "v190","v191","v192","v193","v194","v195","v196","v197","v198","v199",
          "v200","v201","v202","v203","v204","v205","v206","v207","v208","v209",
          "v210","v211","v212","v213","v214","v215","v216","v217","v218","v219",
          "v220","v221","v222","v223","v224","v225","v226","v227");
    // no C epilogue: flush k=15 covers out[1920..2047]
}

extern "C" void kernel_launch(void* const* d_in, const int* in_sizes, int n_in,
                              void* d_out, int out_size, void* d_ws, size_t ws_size,
                              hipStream_t stream) {
    // inputs: 0 input (unused), 1 label, 2 h0, 3 W_ih, 4 W_hh,
    //         5 b_ih, 6 b_hh, 7 W_lin, 8 b_lin
    const int*   label = (const int*)  d_in[1];
    const float* h0    = (const float*)d_in[2];
    const float* W_ih  = (const float*)d_in[3];
    const float* W_hh  = (const float*)d_in[4];
    const float* b_ih  = (const float*)d_in[5];
    const float* b_hh  = (const float*)d_in[6];
    const float* W_lin = (const float*)d_in[7];
    const float* b_lin = (const float*)d_in[8];
    float* out = (float*)d_out;

    lstm_seq_kernel<<<dim3(BATCH), dim3(512), 0, stream>>>(
        label, h0, W_ih, W_hh, b_ih, b_hh, W_lin, b_lin, out);
}

// Round 20
// 1171.555 us; speedup vs baseline: 1.4398x; 1.0169x over previous
//
#include <hip/hip_runtime.h>
#include <math.h>

// Problem constants: T=2048, B=256, H=128, IN_DIM=1, NUM_DATA=4096
#define T_STEPS 2048
#define BATCH   256
#define HDIM    128

__device__ __forceinline__ float fast_rcp(float x) { return __builtin_amdgcn_rcpf(x); }
__device__ __forceinline__ float sigmoid_f(float x) { return fast_rcp(1.0f + __expf(-x)); }
__device__ __forceinline__ float tanh_f(float x) {
    float e = __expf(2.0f * x);
    return 1.0f - 2.0f * fast_rcp(e + 1.0f);
}

#define REP8(M) M(0) M(1) M(2) M(3) M(4) M(5) M(6) M(7)

// R20 = R19 (single 128-slot LDS ring, pk_fma GEMV, DPP quad-combine,
// staggered lgkmcnt; 1191us, ~78% issue-bound) + activation pre-scales
// FOLDED INTO THE WEIGHTS: asm fold multiplies each gate's weights by its
// exp2 scale (i/f/o: -log2e = 0xbfb8aa3b, g: +2log2e = 0x4038aa3b) and the
// bias seeds arrive pre-scaled from C (bit-identical hexfloat constants).
// After the DPP combine the values are exp2-ready -> the two in-loop
// v_pk_mul_f32 are deleted; v_exp reads the combine results directly
// (>=3 intervening insts everywhere - same hazard discipline as R17/R19).
// Register map: h v[0:31], wi v[32:63], wf v[64:95], wg v[96:127],
// wo v[128:159], acc pairs v[160:167], c v168, hn v169, tmp v170,
// jO v171, rdaddr v172, wraddr v174, outbase v176, flushrd v184,
// blin v185, vD v186, WL v[188:219], scaled-bias/4 pairs v[220:227].
__global__ __launch_bounds__(512, 2)
void lstm_seq_kernel(const int*   __restrict__ label,
                     const float* __restrict__ h0,     // (1, 4096, 128)
                     const float* __restrict__ W_ih,   // (512, 1)
                     const float* __restrict__ W_hh,   // (512, 128)
                     const float* __restrict__ b_ih,   // (512,)
                     const float* __restrict__ b_hh,   // (512,)
                     const float* __restrict__ W_lin,  // (1, 128)
                     const float* __restrict__ b_lin,  // (1,)
                     float*       __restrict__ out)    // (T, B, 1)
{
    const int tid   = threadIdx.x;
    const int batch = blockIdx.x;
    const int m     = tid >> 2;     // h element 0..127 (also flush t-slot j)
    const int q     = tid & 3;      // K-quarter 0..3
    const int q8    = q * 8;

    const int ri = m, rf = m + 128, rg = m + 256, ro = m + 384;

    // 128 slots x 144 words = 73728 B. Slot k holds h_state_{k+1}.
    // Slot 127 doubles as h_init scratch for the C prologue.
    __shared__ __attribute__((aligned(16))) float hist[128 * 144];

    const float4* W4 = (const float4*)W_hh;
    const float4* L4 = (const float4*)W_lin;

    // ---- C-side load + fold (used only for step 0, UNSCALED) ----
    #define DECL_W(i) \
        float4 wi##i = W4[ri * 32 + q8 + (i)]; \
        float4 wf##i = W4[rf * 32 + q8 + (i)]; \
        float4 wg##i = W4[rg * 32 + q8 + (i)]; \
        float4 wo##i = W4[ro * 32 + q8 + (i)];
    REP8(DECL_W)

    const float wih_i = W_ih[ri], wih_f = W_ih[rf];
    const float wih_g = W_ih[rg], wih_o = W_ih[ro];
    const float blin  = b_lin[0];

    const float bi_ = b_ih[ri] + b_hh[ri] + wih_i * blin;
    const float bf_ = b_ih[rf] + b_hh[rf] + wih_f * blin;
    const float bg_ = b_ih[rg] + b_hh[rg] + wih_g * blin;
    const float bo_ = b_ih[ro] + b_hh[ro] + wih_o * blin;

    // scaled quarter-seed biases for the asm loop: s_gate * bias / 4.
    // Constants must be BIT-IDENTICAL to the asm literals:
    //   -log2e = 0xBFB8AA3B = -0x1.715476p+0f ; 2log2e = 0x4038AA3B.
    const float SNEG = -0x1.715476p+0f;
    const float SG   =  0x1.715476p+1f;
    const float bi4s = bi_ * 0.25f * SNEG;
    const float bf4s = bf_ * 0.25f * SNEG;
    const float bg4s = bg_ * 0.25f * SG;
    const float bo4s = bo_ * 0.25f * SNEG;

    #define FOLD_W(i) { float4 lv = L4[q8 + (i)]; \
        wi##i.x = fmaf(wih_i, lv.x, wi##i.x); wi##i.y = fmaf(wih_i, lv.y, wi##i.y); \
        wi##i.z = fmaf(wih_i, lv.z, wi##i.z); wi##i.w = fmaf(wih_i, lv.w, wi##i.w); \
        wf##i.x = fmaf(wih_f, lv.x, wf##i.x); wf##i.y = fmaf(wih_f, lv.y, wf##i.y); \
        wf##i.z = fmaf(wih_f, lv.z, wf##i.z); wf##i.w = fmaf(wih_f, lv.w, wf##i.w); \
        wg##i.x = fmaf(wih_g, lv.x, wg##i.x); wg##i.y = fmaf(wih_g, lv.y, wg##i.y); \
        wg##i.z = fmaf(wih_g, lv.z, wg##i.z); wg##i.w = fmaf(wih_g, lv.w, wg##i.w); \
        wo##i.x = fmaf(wih_o, lv.x, wo##i.x); wo##i.y = fmaf(wih_o, lv.y, wo##i.y); \
        wo##i.z = fmaf(wih_o, lv.z, wo##i.z); wo##i.w = fmaf(wih_o, lv.w, wo##i.w); }
    REP8(FOLD_W)

    const int   lane = tid & 63;
    const int   ya0w = lane + ((lane >> 5) << 2);   // word of h[lane] in a slot
    const float wl_a = W_lin[lane];
    const float wl_b = W_lin[lane + 64];
    const int   hword = m + ((m >> 5) << 2);        // element word in a slot

    // ---- init h into slot 127 (scratch; overwritten at t=127) ----
    float* slotI = &hist[144 * 127];
    if (tid < HDIM) slotI[tid + ((tid >> 5) << 2)] = h0[label[batch] * HDIM + tid];
    __syncthreads();

    // y_init (uniform across waves) for the t=0 bias correction
    float p0 = slotI[ya0w] * wl_a + slotI[ya0w + 72] * wl_b;
    #pragma unroll
    for (int off = 1; off < 64; off <<= 1) p0 += __shfl_xor(p0, off, 64);
    const float y0 = p0 + blin;

    const float cbi = bi_ - wih_i * y0;
    const float cbf = bf_ - wih_f * y0;
    const float cbg = bg_ - wih_g * y0;
    const float cbo = bo_ - wih_o * y0;

    // ---- step 0 in C: read slot 127 (init), write state 1 into slot 0 ----
    const float4* hq0 = (const float4*)(slotI + 36 * q);
    float ai = 0.f, af = 0.f, ag = 0.f, ao = 0.f;
    #define DOT4(i) { float4 hv = hq0[(i)]; \
        ai = fmaf(hv.x, wi##i.x, ai); ai = fmaf(hv.y, wi##i.y, ai); \
        ai = fmaf(hv.z, wi##i.z, ai); ai = fmaf(hv.w, wi##i.w, ai); \
        af = fmaf(hv.x, wf##i.x, af); af = fmaf(hv.y, wf##i.y, af); \
        af = fmaf(hv.z, wf##i.z, af); af = fmaf(hv.w, wf##i.w, af); \
        ag = fmaf(hv.x, wg##i.x, ag); ag = fmaf(hv.y, wg##i.y, ag); \
        ag = fmaf(hv.z, wg##i.z, ag); ag = fmaf(hv.w, wg##i.w, ag); \
        ao = fmaf(hv.x, wo##i.x, ao); ao = fmaf(hv.y, wo##i.y, ao); \
        ao = fmaf(hv.z, wo##i.z, ao); ao = fmaf(hv.w, wo##i.w, ao); }
    REP8(DOT4)
    ai += __shfl_xor(ai, 1, 64); af += __shfl_xor(af, 1, 64);
    ag += __shfl_xor(ag, 1, 64); ao += __shfl_xor(ao, 1, 64);
    ai += __shfl_xor(ai, 2, 64); af += __shfl_xor(af, 2, 64);
    ag += __shfl_xor(ag, 2, 64); ao += __shfl_xor(ao, 2, 64);
    const float iv0 = sigmoid_f(ai + cbi);
    const float fv0 = sigmoid_f(af + cbf);
    const float gv0 = tanh_f  (ag + cbg);
    const float ov0 = sigmoid_f(ao + cbo);
    float c = iv0 * gv0;                 // c_prev = 0
    const float hn0 = ov0 * tanh_f(c);
    if (q == 0) hist[hword] = hn0;       // slot 0 = state 1
    __syncthreads();

    // ---- asm operand prep ----
    const unsigned histB = (unsigned)(unsigned long long)(&hist[0]);
    const unsigned vR0 = histB + 144u * (unsigned)q;           // slot0 quarter
    const unsigned hW0 = histB + 576u + 4u * (unsigned)hword;  // slot1 write
    const unsigned vD0 = (unsigned)(-576 + 144 * q - 4 * hword); // read-write
    const unsigned fR0 = histB + 576u * (unsigned)m + 144u * (unsigned)q;
    const unsigned jO0 = 1024u * (unsigned)m;                  // out j*1024
    const unsigned vO0 = 4u * (unsigned)batch;                 // out[0] byte
    const unsigned offI = (unsigned)(ri * 512 + q * 128);
    const unsigned offF = (unsigned)(rf * 512 + q * 128);
    const unsigned offG = (unsigned)(rg * 512 + q * 128);
    const unsigned offO = (unsigned)(ro * 512 + q * 128);
    const unsigned offL = (unsigned)(q * 128);

    asm volatile(
        // ---------------- prologue: fixed-reg setup ----------------
        "v_mov_b32 v220, %[bi]\n\t"
        "v_mov_b32 v221, 0\n\t"
        "v_mov_b32 v222, %[bf]\n\t"
        "v_mov_b32 v223, 0\n\t"
        "v_mov_b32 v224, %[bg]\n\t"
        "v_mov_b32 v225, 0\n\t"
        "v_mov_b32 v226, %[bo]\n\t"
        "v_mov_b32 v227, 0\n\t"
        "v_mov_b32 v185, %[blin]\n\t"
        "v_mov_b32 v168, %[c0]\n\t"
        "v_mov_b32 v172, %[vR]\n\t"
        "v_mov_b32 v174, %[hW]\n\t"
        "v_mov_b32 v186, %[vD]\n\t"
        "v_mov_b32 v184, %[fR]\n\t"
        "v_mov_b32 v171, %[jO]\n\t"
        "v_mov_b32 v176, %[vO]\n\t"
        // q==0 store mask -> s[26:27]
        "v_and_b32 v170, 3, %[tid]\n\t"
        "v_cmp_eq_u32 vcc, 0, v170\n\t"
        "s_nop 4\n\t"
        "s_mov_b64 s[26:27], vcc\n\t"
        // weights: 8x dwordx4 per gate into fixed quads
        "global_load_dwordx4 v[32:35], %[offI], %[whh] offset:0\n\t"
        "global_load_dwordx4 v[36:39], %[offI], %[whh] offset:16\n\t"
        "global_load_dwordx4 v[40:43], %[offI], %[whh] offset:32\n\t"
        "global_load_dwordx4 v[44:47], %[offI], %[whh] offset:48\n\t"
        "global_load_dwordx4 v[48:51], %[offI], %[whh] offset:64\n\t"
        "global_load_dwordx4 v[52:55], %[offI], %[whh] offset:80\n\t"
        "global_load_dwordx4 v[56:59], %[offI], %[whh] offset:96\n\t"
        "global_load_dwordx4 v[60:63], %[offI], %[whh] offset:112\n\t"
        "global_load_dwordx4 v[64:67], %[offF], %[whh] offset:0\n\t"
        "global_load_dwordx4 v[68:71], %[offF], %[whh] offset:16\n\t"
        "global_load_dwordx4 v[72:75], %[offF], %[whh] offset:32\n\t"
        "global_load_dwordx4 v[76:79], %[offF], %[whh] offset:48\n\t"
        "global_load_dwordx4 v[80:83], %[offF], %[whh] offset:64\n\t"
        "global_load_dwordx4 v[84:87], %[offF], %[whh] offset:80\n\t"
        "global_load_dwordx4 v[88:91], %[offF], %[whh] offset:96\n\t"
        "global_load_dwordx4 v[92:95], %[offF], %[whh] offset:112\n\t"
        "global_load_dwordx4 v[96:99], %[offG], %[whh] offset:0\n\t"
        "global_load_dwordx4 v[100:103], %[offG], %[whh] offset:16\n\t"
        "global_load_dwordx4 v[104:107], %[offG], %[whh] offset:32\n\t"
        "global_load_dwordx4 v[108:111], %[offG], %[whh] offset:48\n\t"
        "global_load_dwordx4 v[112:115], %[offG], %[whh] offset:64\n\t"
        "global_load_dwordx4 v[116:119], %[offG], %[whh] offset:80\n\t"
        "global_load_dwordx4 v[120:123], %[offG], %[whh] offset:96\n\t"
        "global_load_dwordx4 v[124:127], %[offG], %[whh] offset:112\n\t"
        "global_load_dwordx4 v[128:131], %[offO], %[whh] offset:0\n\t"
        "global_load_dwordx4 v[132:135], %[offO], %[whh] offset:16\n\t"
        "global_load_dwordx4 v[136:139], %[offO], %[whh] offset:32\n\t"
        "global_load_dwordx4 v[140:143], %[offO], %[whh] offset:48\n\t"
        "global_load_dwordx4 v[144:147], %[offO], %[whh] offset:64\n\t"
        "global_load_dwordx4 v[148:151], %[offO], %[whh] offset:80\n\t"
        "global_load_dwordx4 v[152:155], %[offO], %[whh] offset:96\n\t"
        "global_load_dwordx4 v[156:159], %[offO], %[whh] offset:112\n\t"
        // W_lin quarter-slice -> persistent v[188:219]
        "global_load_dwordx4 v[188:191], %[offL], %[wlin] offset:0\n\t"
        "global_load_dwordx4 v[192:195], %[offL], %[wlin] offset:16\n\t"
        "global_load_dwordx4 v[196:199], %[offL], %[wlin] offset:32\n\t"
        "global_load_dwordx4 v[200:203], %[offL], %[wlin] offset:48\n\t"
        "global_load_dwordx4 v[204:207], %[offL], %[wlin] offset:64\n\t"
        "global_load_dwordx4 v[208:211], %[offL], %[wlin] offset:80\n\t"
        "global_load_dwordx4 v[212:215], %[offL], %[wlin] offset:96\n\t"
        "global_load_dwordx4 v[216:219], %[offL], %[wlin] offset:112\n\t"
        "s_waitcnt vmcnt(0)\n\t"
        // fold: W' = W + wih * W_lin, then pre-scale by the gate's exp2
        // constant (i/f/o: -log2e, g: 2log2e) so the in-loop combine output
        // feeds v_exp directly.
        ".set K_I, 0\n"
        ".rept 32\n"
        " v_fma_f32 v[32+K_I],  %[wihi], v[188+K_I], v[32+K_I]\n"
        " v_fma_f32 v[64+K_I],  %[wihf], v[188+K_I], v[64+K_I]\n"
        " v_fma_f32 v[96+K_I],  %[wihg], v[188+K_I], v[96+K_I]\n"
        " v_fma_f32 v[128+K_I], %[wiho], v[188+K_I], v[128+K_I]\n"
        " .set K_I, K_I+1\n"
        ".endr\n"
        ".set K_I, 0\n"
        ".rept 32\n"
        " v_mul_f32 v[32+K_I],  0xbfb8aa3b, v[32+K_I]\n"
        " v_mul_f32 v[64+K_I],  0xbfb8aa3b, v[64+K_I]\n"
        " v_mul_f32 v[96+K_I],  0x4038aa3b, v[96+K_I]\n"
        " v_mul_f32 v[128+K_I], 0xbfb8aa3b, v[128+K_I]\n"
        " .set K_I, K_I+1\n"
        ".endr\n"
        "s_movk_i32 s24, 1\n\t"
        // ---------------- main loop: t = 1 .. 2047 ----------------
        "1:\n\t"
        // h quarter: 8x b128 broadcast reads from slot t-1
        "ds_read_b128 v[0:3],   v172\n\t"
        "ds_read_b128 v[4:7],   v172 offset:16\n\t"
        "ds_read_b128 v[8:11],  v172 offset:32\n\t"
        "ds_read_b128 v[12:15], v172 offset:48\n\t"
        "ds_read_b128 v[16:19], v172 offset:64\n\t"
        "ds_read_b128 v[20:23], v172 offset:80\n\t"
        "ds_read_b128 v[24:27], v172 offset:96\n\t"
        "ds_read_b128 v[28:31], v172 offset:112\n\t"
        // ---- packed GEMV: pairs 0-3 once reads 0-1 land ----
        "s_waitcnt lgkmcnt(6)\n\t"
        "v_pk_fma_f32 v[160:161], v[0:1], v[32:33], v[220:221]\n\t"
        "v_pk_fma_f32 v[162:163], v[0:1], v[64:65], v[222:223]\n\t"
        "v_pk_fma_f32 v[164:165], v[0:1], v[96:97], v[224:225]\n\t"
        "v_pk_fma_f32 v[166:167], v[0:1], v[128:129], v[226:227]\n\t"
        ".set K_I, 2\n"
        ".rept 3\n"
        " v_pk_fma_f32 v[160:161], v[K_I:K_I+1], v[32+K_I:33+K_I], v[160:161]\n"
        " v_pk_fma_f32 v[162:163], v[K_I:K_I+1], v[64+K_I:65+K_I], v[162:163]\n"
        " v_pk_fma_f32 v[164:165], v[K_I:K_I+1], v[96+K_I:97+K_I], v[164:165]\n"
        " v_pk_fma_f32 v[166:167], v[K_I:K_I+1], v[128+K_I:129+K_I], v[166:167]\n"
        " .set K_I, K_I+2\n"
        ".endr\n"
        "s_waitcnt lgkmcnt(4)\n\t"
        ".rept 4\n"
        " v_pk_fma_f32 v[160:161], v[K_I:K_I+1], v[32+K_I:33+K_I], v[160:161]\n"
        " v_pk_fma_f32 v[162:163], v[K_I:K_I+1], v[64+K_I:65+K_I], v[162:163]\n"
        " v_pk_fma_f32 v[164:165], v[K_I:K_I+1], v[96+K_I:97+K_I], v[164:165]\n"
        " v_pk_fma_f32 v[166:167], v[K_I:K_I+1], v[128+K_I:129+K_I], v[166:167]\n"
        " .set K_I, K_I+2\n"
        ".endr\n"
        "s_waitcnt lgkmcnt(2)\n\t"
        ".rept 4\n"
        " v_pk_fma_f32 v[160:161], v[K_I:K_I+1], v[32+K_I:33+K_I], v[160:161]\n"
        " v_pk_fma_f32 v[162:163], v[K_I:K_I+1], v[64+K_I:65+K_I], v[162:163]\n"
        " v_pk_fma_f32 v[164:165], v[K_I:K_I+1], v[96+K_I:97+K_I], v[164:165]\n"
        " v_pk_fma_f32 v[166:167], v[K_I:K_I+1], v[128+K_I:129+K_I], v[166:167]\n"
        " .set K_I, K_I+2\n"
        ".endr\n"
        "s_waitcnt lgkmcnt(0)\n\t"
        ".rept 4\n"
        " v_pk_fma_f32 v[160:161], v[K_I:K_I+1], v[32+K_I:33+K_I], v[160:161]\n"
        " v_pk_fma_f32 v[162:163], v[K_I:K_I+1], v[64+K_I:65+K_I], v[162:163]\n"
        " v_pk_fma_f32 v[164:165], v[K_I:K_I+1], v[96+K_I:97+K_I], v[164:165]\n"
        " v_pk_fma_f32 v[166:167], v[K_I:K_I+1], v[128+K_I:129+K_I], v[166:167]\n"
        " .set K_I, K_I+2\n"
        ".endr\n"
        // ---- collapse lo+hi: (i,f)->160,161 (g,o)->164,165 (pre-scaled) ----
        "v_add_f32 v160, v160, v161\n\t"
        "v_add_f32 v161, v162, v163\n\t"
        "v_add_f32 v164, v164, v165\n\t"
        "v_add_f32 v165, v166, v167\n\t"
        // ---- quarter-combine in-register: DPP quad_perm xor1 then xor2 ----
        "v_add_f32_dpp v160, v160, v160 quad_perm:[1,0,3,2] row_mask:0xf bank_mask:0xf\n\t"
        "v_add_f32_dpp v161, v161, v161 quad_perm:[1,0,3,2] row_mask:0xf bank_mask:0xf\n\t"
        "v_add_f32_dpp v164, v164, v164 quad_perm:[1,0,3,2] row_mask:0xf bank_mask:0xf\n\t"
        "v_add_f32_dpp v165, v165, v165 quad_perm:[1,0,3,2] row_mask:0xf bank_mask:0xf\n\t"
        "v_add_f32_dpp v160, v160, v160 quad_perm:[2,3,0,1] row_mask:0xf bank_mask:0xf\n\t"
        "v_add_f32_dpp v161, v161, v161 quad_perm:[2,3,0,1] row_mask:0xf bank_mask:0xf\n\t"
        "v_add_f32_dpp v164, v164, v164 quad_perm:[2,3,0,1] row_mask:0xf bank_mask:0xf\n\t"
        "v_add_f32_dpp v165, v165, v165 quad_perm:[2,3,0,1] row_mask:0xf bank_mask:0xf\n\t"
        // ---- activations: values already exp2-scaled; trans-safe spacing ----
        "v_exp_f32 v160, v160\n\t"               // i (gap 3 from its DPP)
        "v_exp_f32 v161, v161\n\t"
        "v_exp_f32 v164, v164\n\t"
        "v_exp_f32 v165, v165\n\t"
        "v_add_f32 v164, 1.0, v164\n\t"          // g-denom first (gap 3)
        "v_add_f32 v165, 1.0, v165\n\t"
        "v_add_f32 v160, 1.0, v160\n\t"
        "v_add_f32 v161, 1.0, v161\n\t"
        "v_rcp_f32 v164, v164\n\t"               // g-denom (gap 3)
        "v_rcp_f32 v160, v160\n\t"               // i = sigmoid
        "v_rcp_f32 v161, v161\n\t"               // f = sigmoid
        "v_rcp_f32 v165, v165\n\t"               // o = sigmoid
        "v_fma_f32 v164, -2.0, v164, 1.0\n\t"    // g = tanh (gap 3)
        "v_mul_f32 v170, v160, v164\n\t"         // i*g (gap 3 from rcp160)
        "v_fma_f32 v168, v161, v168, v170\n\t"   // c = f*c + i*g (gap 3)
        // tanh(c) with explicit wait states
        "v_mul_f32 v170, 0x4038aa3b, v168\n\t"
        "v_exp_f32 v170, v170\n\t"
        "s_nop 1\n\t"
        "v_add_f32 v170, 1.0, v170\n\t"
        "v_rcp_f32 v170, v170\n\t"
        "s_nop 1\n\t"
        "v_fma_f32 v169, -2.0, v170, 1.0\n\t"
        "v_mul_f32 v169, v165, v169\n\t"         // hn = o * tanh(c)
        // publish h into ring slot t (q==0 lanes)
        "s_mov_b64 s[22:23], exec\n\t"
        "s_mov_b64 exec, s[26:27]\n\t"
        "ds_write_b32 v174, v169\n\t"
        "s_mov_b64 exec, s[22:23]\n\t"
        // advance: write += 576; next read = write + vD (pre-wrap value!)
        "v_add_u32 v174, 0x240, v174\n\t"
        "v_add_u32 v172, v174, v186\n\t"
        "s_waitcnt lgkmcnt(0)\n\t"
        "s_barrier\n\t"
        // ---- flush every 128 steps: out[...] = hist[j].WL + blin ----
        "s_and_b32 s20, s24, 127\n\t"
        "s_cmp_lg_u32 s20, 127\n\t"
        "s_cbranch_scc1 3f\n\t"
        "v_add_u32 v174, 0xfffee000, v174\n\t"   // write base wrap: -73728
        "ds_read_b128 v[0:3],   v184\n\t"
        "ds_read_b128 v[4:7],   v184 offset:16\n\t"
        "ds_read_b128 v[8:11],  v184 offset:32\n\t"
        "ds_read_b128 v[12:15], v184 offset:48\n\t"
        "ds_read_b128 v[16:19], v184 offset:64\n\t"
        "ds_read_b128 v[20:23], v184 offset:80\n\t"
        "ds_read_b128 v[24:27], v184 offset:96\n\t"
        "ds_read_b128 v[28:31], v184 offset:112\n\t"
        "v_mov_b32 v164, 0\n\t"
        "s_waitcnt lgkmcnt(0)\n\t"
        ".set K_I, 0\n"
        ".rept 32\n"
        " v_fma_f32 v164, v[0+K_I], v[188+K_I], v164\n"
        " .set K_I, K_I+1\n"
        ".endr\n"
        "s_nop 1\n\t"
        "v_add_f32_dpp v164, v164, v164 quad_perm:[1,0,3,2] row_mask:0xf bank_mask:0xf\n\t"
        "s_nop 1\n\t"
        "v_add_f32_dpp v164, v164, v164 quad_perm:[2,3,0,1] row_mask:0xf bank_mask:0xf\n\t"
        "v_add_f32 v164, v164, v185\n\t"         // + b_lin
        "v_add_u32 v170, v176, v171\n\t"         // out byte = base + j*1024
        "s_mov_b64 s[22:23], exec\n\t"
        "s_mov_b64 exec, s[26:27]\n\t"
        "global_store_dword v170, v164, %[outp]\n\t"
        "s_mov_b64 exec, s[22:23]\n\t"
        "v_add_u32 v176, 0x20000, v176\n\t"      // out base += 128*256*4
        "s_barrier\n\t"                           // protect hist vs next iter
        "3:\n\t"
        "s_add_i32 s24, s24, 1\n\t"
        "s_cmp_lt_i32 s24, 2048\n\t"
        "s_cbranch_scc1 1b\n\t"
        :
        : [offI]"v"(offI), [offF]"v"(offF), [offG]"v"(offG), [offO]"v"(offO),
          [offL]"v"(offL), [whh]"s"(W_hh), [wlin]"s"(W_lin), [outp]"s"(out),
          [wihi]"v"(wih_i), [wihf]"v"(wih_f), [wihg]"v"(wih_g), [wiho]"v"(wih_o),
          [bi]"v"(bi4s), [bf]"v"(bf4s), [bg]"v"(bg4s), [bo]"v"(bo4s),
          [blin]"v"(blin), [c0]"v"(c),
          [vR]"v"(vR0), [hW]"v"(hW0), [vD]"v"(vD0), [fR]"v"(fR0),
          [jO]"v"(jO0), [vO]"v"(vO0), [tid]"v"(tid)
        : "memory", "scc", "vcc", "s20","s21","s22","s23","s24","s25","s26","s27",
          "v0","v1","v2","v3","v4","v5","v6","v7","v8","v9",
          "v10","v11","v12","v13","v14","v15","v16","v17","v18","v19",
          "v20","v21","v22","v23","v24","v25","v26","v27","v28","v29",
          "v30","v31","v32","v33","v34","v35","v36","v37","v38","v39",
          "v40","v41","v42","v43","v44","v45","v46","v47","v48","v49",
          "v50","v51","v52","v53","v54","v55","v56","v57","v58","v59",
          "v60","v61","v62","v63","v64","v65","v66","v67","v68","v69",
          "v70","v71","v72","v73","v74","v75","v76","v77","v78","v79",
          "v80","v81","v82","v83","v84","v85","v86","v87","v88","v89",
          "v90","v91","v92","v93","v94","v95","v96","v97","v98","v99",
          "v100","v101","v102","v103","v104","v105","v106","v107","v108","v109",
          "v110","v111","v112","v113","v114","v115","v116","v117","v118","v119",
          "v120","v121","v122","v123","v124","v125","v126","v127","v128","v129",
          "v130","v131","v132","v133","v134","v135","v136","v137","v138","v139",
          "v140","v141","v142","v143","v144","v145","v146","v147","v148","v149",
          "v150","v151","v152","v153","v154","v155","v156","v157","v158","v159",
          "v160","v161","v162","v163","v164","v165","v166","v167","v168","v169",
          "v170","v171","v172","v173","v174","v175","v176","v177","v178","v179",
          "v180","v181","v182","v183","v184","v185","v186","v187","v188","v189",
          "v190","v191","v192","v193","v194","v195","v196","v197","v198","v199",
          "v200","v201","v202","v203","v204","v205","v206","v207","v208","v209",
          "v210","v211","v212","v213","v214","v215","v216","v217","v218","v219",
          "v220","v221","v222","v223","v224","v225","v226","v227");
    // no C epilogue: flush k=15 covers out[1920..2047]
}

extern "C" void kernel_launch(void* const* d_in, const int* in_sizes, int n_in,
                              void* d_out, int out_size, void* d_ws, size_t ws_size,
                              hipStream_t stream) {
    // inputs: 0 input (unused), 1 label, 2 h0, 3 W_ih, 4 W_hh,
    //         5 b_ih, 6 b_hh, 7 W_lin, 8 b_lin
    const int*   label = (const int*)  d_in[1];
    const float* h0    = (const float*)d_in[2];
    const float* W_ih  = (const float*)d_in[3];
    const float* W_hh  = (const float*)d_in[4];
    const float* b_ih  = (const float*)d_in[5];
    const float* b_hh  = (const float*)d_in[6];
    const float* W_lin = (const float*)d_in[7];
    const float* b_lin = (const float*)d_in[8];
    float* out = (float*)d_out;

    lstm_seq_kernel<<<dim3(BATCH), dim3(512), 0, stream>>>(
        label, h0, W_ih, W_hh, b_ih, b_hh, W_lin, b_lin, out);
}